// Round 1
// baseline (1437.318 us; speedup 1.0000x reference)
//
#include <hip/hip_runtime.h>
#include <hip/hip_bf16.h>
#include <math.h>

using bf16 = __hip_bfloat16;

static constexpr int CDIM   = 192;
static constexpr int HEADS  = 6;
static constexpr int CP     = 32;     // CDIM / HEADS
static constexpr int HIDDEN = 384;
static constexpr int HImg   = 128;
static constexpr int WImg   = 128;
static constexpr int HW     = HImg * WImg;   // 16384
static constexpr int BATCH  = 4;
static constexpr int PCHUNK = 256;    // attn contraction chunk

template<typename T> __device__ inline float tof(T v);
template<> __device__ inline float tof<float>(float v){ return v; }
template<> __device__ inline float tof<bf16>(bf16 v){ return __bfloat162float(v); }

template<typename T> __device__ inline T fromf(float v);
template<> __device__ inline float fromf<float>(float v){ return v; }
template<> __device__ inline bf16  fromf<bf16>(float v){ return __float2bfloat16(v); }

__device__ inline float gelu_exact(float x){
    return 0.5f * x * (1.0f + erff(x * 0.70710678118654752440f));
}

// ---------------- LayerNorm over channel dim, NCHW, per pixel ----------------
__global__ __launch_bounds__(256) void ln_kernel(
    const float* __restrict__ in, const float* __restrict__ g,
    const float* __restrict__ b, float* __restrict__ out)
{
    int n = blockIdx.x * 256 + threadIdx.x;       // pixel
    int z = blockIdx.y;                           // batch
    const float* p = in  + (size_t)z * CDIM * HW + n;
    float*       q = out + (size_t)z * CDIM * HW + n;
    float s = 0.f, s2 = 0.f;
    for (int c = 0; c < CDIM; ++c){
        float v = p[(size_t)c * HW];
        s += v; s2 += v * v;
    }
    float mean = s * (1.0f / CDIM);
    float var  = s2 * (1.0f / CDIM) - mean * mean;
    float r = rsqrtf(var + 1e-5f);
    for (int c = 0; c < CDIM; ++c){
        float v = p[(size_t)c * HW];
        q[(size_t)c * HW] = (v - mean) * r * g[c] + b[c];
    }
}

// ---------------- GEMM: C[M,N] = W[M,K] @ X[K,N], batched over z -------------
// EPI: 0 = none, 1 = add residual (res, [M,N] per batch), 2 = bias + exact GELU
template<typename XT, typename CT, int EPI>
__global__ __launch_bounds__(256) void gemm_kernel(
    const float* __restrict__ Wt, const XT* __restrict__ X, CT* __restrict__ C,
    const float* __restrict__ bias, const float* __restrict__ res,
    int M, int N, int K)
{
    int z = blockIdx.z;
    const XT* Xb = X + (size_t)z * K * N;
    CT*       Cb = C + (size_t)z * M * N;
    int n0 = blockIdx.x * 64, m0 = blockIdx.y * 64;
    __shared__ float Ws[16][65];
    __shared__ float Xs[16][65];
    int tid = threadIdx.x;
    int tn = tid & 15, tm = tid >> 4;
    float acc[4][4] = {};
    for (int k0 = 0; k0 < K; k0 += 16){
        for (int i = tid; i < 1024; i += 256){
            int m = i >> 4, kk = i & 15;
            Ws[kk][m] = Wt[(size_t)(m0 + m) * K + k0 + kk];
        }
        for (int i = tid; i < 1024; i += 256){
            int kk = i >> 6, n = i & 63;
            Xs[kk][n] = tof<XT>(Xb[(size_t)(k0 + kk) * N + n0 + n]);
        }
        __syncthreads();
        #pragma unroll
        for (int kk = 0; kk < 16; ++kk){
            float a[4], bv[4];
            #pragma unroll
            for (int i = 0; i < 4; ++i) a[i]  = Ws[kk][tm * 4 + i];
            #pragma unroll
            for (int j = 0; j < 4; ++j) bv[j] = Xs[kk][tn * 4 + j];
            #pragma unroll
            for (int i = 0; i < 4; ++i)
                #pragma unroll
                for (int j = 0; j < 4; ++j)
                    acc[i][j] = fmaf(a[i], bv[j], acc[i][j]);
        }
        __syncthreads();
    }
    #pragma unroll
    for (int i = 0; i < 4; ++i){
        int m = m0 + tm * 4 + i;
        #pragma unroll
        for (int j = 0; j < 4; ++j){
            int n = n0 + tn * 4 + j;
            float v = acc[i][j];
            if (EPI == 1) v += res[(size_t)z * M * N + (size_t)m * N + n];
            if (EPI == 2) v = gelu_exact(v + bias[m]);
            Cb[(size_t)m * N + n] = fromf<CT>(v);
        }
    }
}

// ---------------- depthwise 3x3, pad 1, 576 channels -------------------------
__global__ __launch_bounds__(256) void dw_kernel(
    const bf16* __restrict__ in, const float* __restrict__ wdw, bf16* __restrict__ out)
{
    int ch = blockIdx.y, z = blockIdx.z;
    int n = blockIdx.x * 256 + threadIdx.x;
    int yy = n >> 7, xx = n & 127;
    const bf16* p = in + ((size_t)z * 3 * CDIM + ch) * HW;
    float acc = 0.f;
    #pragma unroll
    for (int dy = 0; dy < 3; ++dy){
        int iy = yy + dy - 1;
        if (iy < 0 || iy >= HImg) continue;
        #pragma unroll
        for (int dx = 0; dx < 3; ++dx){
            int ix = xx + dx - 1;
            if (ix < 0 || ix >= WImg) continue;
            acc += wdw[ch * 9 + dy * 3 + dx] * tof<bf16>(p[iy * WImg + ix]);
        }
    }
    out[((size_t)z * 3 * CDIM + ch) * HW + n] = fromf<bf16>(acc);
}

// ---------------- l2-norm inverses for q and k over hw -----------------------
__global__ __launch_bounds__(256) void l2inv_kernel(
    const bf16* __restrict__ qkv, float* __restrict__ invq, float* __restrict__ invk)
{
    int bx = blockIdx.x;              // [0, 2*CDIM)
    int z  = blockIdx.y;
    int which = bx / CDIM;            // 0 = q, 1 = k
    int c     = bx % CDIM;
    const bf16* p = qkv + ((size_t)z * 3 * CDIM + which * CDIM + c) * HW;
    float s = 0.f;
    for (int i = threadIdx.x; i < HW; i += 256){
        float v = tof<bf16>(p[i]);
        s += v * v;
    }
    #pragma unroll
    for (int m = 1; m < 64; m <<= 1) s += __shfl_xor(s, m, 64);
    __shared__ float red[4];
    if ((threadIdx.x & 63) == 0) red[threadIdx.x >> 6] = s;
    __syncthreads();
    if (threadIdx.x == 0){
        float t = red[0] + red[1] + red[2] + red[3];
        float inv = 1.0f / fmaxf(sqrtf(t), 1e-12f);
        (which ? invk : invq)[z * CDIM + c] = inv;
    }
}

// ---------------- attn partials: per chunk of PCHUNK pixels ------------------
__global__ __launch_bounds__(256) void attn_qk_kernel(
    const bf16* __restrict__ qkv, const float* __restrict__ invq,
    const float* __restrict__ invk, const float* __restrict__ temp,
    float* __restrict__ part)
{
    int chunk = blockIdx.x;           // HW / PCHUNK chunks
    int h = blockIdx.y, z = blockIdx.z;
    __shared__ bf16 qs[CP][PCHUNK];
    __shared__ bf16 ks[CP][PCHUNK];
    int n0 = chunk * PCHUNK;
    const bf16* qb = qkv + ((size_t)z * 3 * CDIM + h * CP) * HW;
    const bf16* kb = qkv + ((size_t)z * 3 * CDIM + CDIM + h * CP) * HW;
    for (int i = threadIdx.x; i < CP * PCHUNK; i += 256){
        int r = i / PCHUNK, p = i % PCHUNK;
        qs[r][p] = qb[(size_t)r * HW + n0 + p];
        ks[r][p] = kb[(size_t)r * HW + n0 + p];
    }
    __syncthreads();
    int c  = threadIdx.x >> 3;
    int d0 = (threadIdx.x & 7) * 4;
    float acc[4] = {0.f, 0.f, 0.f, 0.f};
    for (int p = 0; p < PCHUNK; ++p){
        float qv = tof<bf16>(qs[c][p]);
        #pragma unroll
        for (int j = 0; j < 4; ++j)
            acc[j] = fmaf(qv, tof<bf16>(ks[d0 + j][p]), acc[j]);
    }
    float sc = invq[z * CDIM + h * CP + c] * temp[h];
    size_t base = ((size_t)chunk * BATCH * HEADS + (size_t)z * HEADS + h) * CP * CP
                + c * CP + d0;
    #pragma unroll
    for (int j = 0; j < 4; ++j)
        part[base + j] = acc[j] * sc * invk[z * CDIM + h * CP + d0 + j];
}

__global__ __launch_bounds__(256) void attn_reduce_kernel(
    const float* __restrict__ part, float* __restrict__ attn)
{
    int idx = blockIdx.x * 256 + threadIdx.x;      // < BATCH*HEADS*CP*CP
    float s = 0.f;
    for (int ch = 0; ch < HW / PCHUNK; ++ch)
        s += part[(size_t)ch * (BATCH * HEADS * CP * CP) + idx];
    attn[idx] = s;
}

// ---------------- 3x3 conv over head-channels on [HEADS, CP, CP] -------------
__global__ __launch_bounds__(256) void headconv_kernel(
    const float* __restrict__ attn, const float* __restrict__ wh, float* __restrict__ attn2)
{
    int oh = blockIdx.x, z = blockIdx.y;
    __shared__ float wsm[HEADS * 9];
    if (threadIdx.x < HEADS * 9) wsm[threadIdx.x] = wh[oh * HEADS * 9 + threadIdx.x];
    __syncthreads();
    for (int idx = threadIdx.x; idx < CP * CP; idx += 256){
        int i = idx >> 5, j = idx & 31;
        float acc = 0.f;
        for (int ih = 0; ih < HEADS; ++ih){
            const float* ab = attn + ((size_t)(z * HEADS + ih)) * CP * CP;
            #pragma unroll
            for (int dy = 0; dy < 3; ++dy){
                int ii = i + dy - 1;
                if (ii < 0 || ii >= CP) continue;
                #pragma unroll
                for (int dx = 0; dx < 3; ++dx){
                    int jj = j + dx - 1;
                    if (jj < 0 || jj >= CP) continue;
                    acc += wsm[ih * 9 + dy * 3 + dx] * ab[ii * CP + jj];
                }
            }
        }
        attn2[((size_t)(z * HEADS + oh)) * CP * CP + idx] = acc;
    }
}

// ---------------- softmax over last dim (32) ---------------------------------
__global__ __launch_bounds__(1024) void softmax_kernel(float* __restrict__ attn2)
{
    int h = blockIdx.x, z = blockIdx.y;
    float* p = attn2 + ((size_t)(z * HEADS + h)) * CP * CP;
    int r = threadIdx.x >> 5, j = threadIdx.x & 31;
    float v = p[r * CP + j];
    float mx = v;
    #pragma unroll
    for (int m = 1; m < 32; m <<= 1) mx = fmaxf(mx, __shfl_xor(mx, m, 32));
    float e = expf(v - mx);
    float sum = e;
    #pragma unroll
    for (int m = 1; m < 32; m <<= 1) sum += __shfl_xor(sum, m, 32);
    p[r * CP + j] = e / sum;
}

// ---------------- out = attn2 @ v --------------------------------------------
__global__ __launch_bounds__(256) void av_kernel(
    const float* __restrict__ attn2, const bf16* __restrict__ qkv, float* __restrict__ out)
{
    int h = blockIdx.y, z = blockIdx.z;
    int n = blockIdx.x * 256 + threadIdx.x;
    __shared__ float As[CP][CP];
    for (int i = threadIdx.x; i < CP * CP; i += 256)
        As[i >> 5][i & 31] = attn2[((size_t)(z * HEADS + h)) * CP * CP + i];
    __syncthreads();
    const bf16* vb = qkv + ((size_t)z * 3 * CDIM + 2 * CDIM + h * CP) * HW + n;
    float vreg[CP];
    #pragma unroll
    for (int d = 0; d < CP; ++d) vreg[d] = tof<bf16>(vb[(size_t)d * HW]);
    float* ob = out + ((size_t)z * CDIM + h * CP) * HW + n;
    for (int c = 0; c < CP; ++c){
        float acc = 0.f;
        #pragma unroll
        for (int d = 0; d < CP; ++d) acc = fmaf(As[c][d], vreg[d], acc);
        ob[(size_t)c * HW] = acc;
    }
}

// ---------------- spatial gate: sigmoid(conv3x3(y, 192->1)) ------------------
__global__ __launch_bounds__(256) void gate_kernel(
    const float* __restrict__ y, const float* __restrict__ wsa,
    const float* __restrict__ bsa, float* __restrict__ gate)
{
    __shared__ float wsm[CDIM * 9];
    for (int i = threadIdx.x; i < CDIM * 9; i += 256) wsm[i] = wsa[i];
    __syncthreads();
    int z = blockIdx.y;
    int n = blockIdx.x * 256 + threadIdx.x;
    int yy = n >> 7, xx = n & 127;
    const float* yb = y + (size_t)z * CDIM * HW;
    float acc = bsa[0];
    for (int c = 0; c < CDIM; ++c){
        const float* pc = yb + (size_t)c * HW;
        #pragma unroll
        for (int dy = 0; dy < 3; ++dy){
            int iy = yy + dy - 1;
            if (iy < 0 || iy >= HImg) continue;
            #pragma unroll
            for (int dx = 0; dx < 3; ++dx){
                int ix = xx + dx - 1;
                if (ix < 0 || ix >= WImg) continue;
                acc += wsm[c * 9 + dy * 3 + dx] * pc[iy * WImg + ix];
            }
        }
    }
    gate[(size_t)z * HW + n] = 1.0f / (1.0f + expf(-acc));
}

// ---------------- final: out = x2 + y2 * gate --------------------------------
__global__ __launch_bounds__(256) void final_kernel(
    const float* __restrict__ x2, const float* __restrict__ y2,
    const float* __restrict__ gate, float* __restrict__ out)
{
    size_t idx = (size_t)blockIdx.x * 256 + threadIdx.x;
    int n = (int)(idx % HW);
    int z = (int)(idx / ((size_t)CDIM * HW));
    out[idx] = x2[idx] + y2[idx] * gate[(size_t)z * HW + n];
}

extern "C" void kernel_launch(void* const* d_in, const int* in_sizes, int n_in,
                              void* d_out, int out_size, void* d_ws, size_t ws_size,
                              hipStream_t stream)
{
    const float* x      = (const float*)d_in[0];
    const float* g1     = (const float*)d_in[1];
    const float* b1     = (const float*)d_in[2];
    const float* w_qkv  = (const float*)d_in[3];
    const float* w_dw   = (const float*)d_in[4];
    const float* temp   = (const float*)d_in[5];
    const float* w_head = (const float*)d_in[6];
    const float* w_proj = (const float*)d_in[7];
    const float* g2     = (const float*)d_in[8];
    const float* b2     = (const float*)d_in[9];
    const float* w_fc1  = (const float*)d_in[10];
    const float* b_fc1  = (const float*)d_in[11];
    const float* w_fc2  = (const float*)d_in[12];
    const float* b_fc2  = (const float*)d_in[13];
    const float* w_sa   = (const float*)d_in[14];
    const float* b_sa   = (const float*)d_in[15];
    float* out = (float*)d_out;

    char* ws = (char*)d_ws;
    const size_t FULL = (size_t)BATCH * CDIM * HW;      // 12.58M elems

    // region 0: FULL f32  (x1 -> ln2 -> y2)
    float* x1  = (float*)ws;
    float* ln2 = x1;
    float* y2  = x1;
    // region A: 3*FULL bf16 (qkv) -> FULL f32 (attn_out) -> HIDDEN*HW*B bf16 (y1)
    char* regA = ws + FULL * 4;
    bf16*  qkvA     = (bf16*)regA;
    float* attn_out = (float*)regA;
    bf16*  y1       = (bf16*)regA;
    // region B: 3*FULL bf16 (dw qkv) -> FULL f32 (x2)
    char* regB = regA + FULL * 3 * 2;
    bf16*  dwB = (bf16*)regB;
    float* x2  = (float*)regB;
    // small region
    char* smallr = regB + FULL * 3 * 2;
    float* invq  = (float*)smallr;                          // B*CDIM
    float* invk  = invq + BATCH * CDIM;                     // B*CDIM
    float* attn  = invk + BATCH * CDIM;                     // B*HEADS*CP*CP
    float* attn2 = attn + BATCH * HEADS * CP * CP;
    float* gate  = attn2 + BATCH * HEADS * CP * CP;         // B*HW
    float* part  = gate + BATCH * HW;                       // (HW/PCHUNK)*B*HEADS*CP*CP

    dim3 blk(256);

    // 1. LayerNorm1 (residual uses normed x per reference)
    ln_kernel<<<dim3(HW / 256, BATCH), blk, 0, stream>>>(x, g1, b1, x1);
    // 2. qkv 1x1 conv (GEMM 576x16384x192), bf16 out
    gemm_kernel<float, bf16, 0><<<dim3(HW / 64, (3 * CDIM) / 64, BATCH), blk, 0, stream>>>(
        w_qkv, x1, qkvA, nullptr, nullptr, 3 * CDIM, HW, CDIM);
    // 3. depthwise 3x3
    dw_kernel<<<dim3(HW / 256, 3 * CDIM, BATCH), blk, 0, stream>>>(qkvA, w_dw, dwB);
    // 4. l2 norm inverses for q,k
    l2inv_kernel<<<dim3(2 * CDIM, BATCH), blk, 0, stream>>>(dwB, invq, invk);
    // 5. attn partial dot-products over pixel chunks
    attn_qk_kernel<<<dim3(HW / PCHUNK, HEADS, BATCH), blk, 0, stream>>>(
        dwB, invq, invk, temp, part);
    // 6. deterministic reduction of partials
    attn_reduce_kernel<<<dim3((BATCH * HEADS * CP * CP) / 256), blk, 0, stream>>>(part, attn);
    // 7. 3x3 conv over head channels
    headconv_kernel<<<dim3(HEADS, BATCH), blk, 0, stream>>>(attn, w_head, attn2);
    // 8. softmax over last dim
    softmax_kernel<<<dim3(HEADS, BATCH), dim3(1024), 0, stream>>>(attn2);
    // 9. out = attn @ v
    av_kernel<<<dim3(HW / 256, HEADS, BATCH), blk, 0, stream>>>(attn2, dwB, attn_out);
    // 10. proj 1x1 + residual(x1) -> x2
    gemm_kernel<float, float, 1><<<dim3(HW / 64, CDIM / 64, BATCH), blk, 0, stream>>>(
        w_proj, attn_out, x2, nullptr, x1, CDIM, HW, CDIM);
    // 11. LayerNorm2
    ln_kernel<<<dim3(HW / 256, BATCH), blk, 0, stream>>>(x2, g2, b2, ln2);
    // 12. fc1 + bias + gelu -> bf16
    gemm_kernel<float, bf16, 2><<<dim3(HW / 64, HIDDEN / 64, BATCH), blk, 0, stream>>>(
        w_fc1, ln2, y1, b_fc1, nullptr, HIDDEN, HW, CDIM);
    // 13. fc2 + bias + gelu -> f32
    gemm_kernel<bf16, float, 2><<<dim3(HW / 64, CDIM / 64, BATCH), blk, 0, stream>>>(
        w_fc2, y1, y2, b_fc2, nullptr, CDIM, HW, HIDDEN);
    // 14. spatial gate
    gate_kernel<<<dim3(HW / 256, BATCH), blk, 0, stream>>>(y2, w_sa, b_sa, gate);
    // 15. final: out = x2 + y2*gate
    final_kernel<<<dim3((int)((FULL) / 256)), blk, 0, stream>>>(x2, y2, gate, out);
}

// Round 2
// 789.808 us; speedup vs baseline: 1.8198x; 1.8198x over previous
//
#include <hip/hip_runtime.h>
#include <hip/hip_bf16.h>
#include <math.h>

using bf16 = __hip_bfloat16;

static constexpr int CDIM   = 192;
static constexpr int HEADS  = 6;
static constexpr int CP     = 32;     // CDIM / HEADS
static constexpr int HIDDEN = 384;
static constexpr int HImg   = 128;
static constexpr int WImg   = 128;
static constexpr int HW     = HImg * WImg;   // 16384
static constexpr int BATCH  = 4;
static constexpr int PCHUNK = 256;    // attn contraction chunk

typedef __attribute__((ext_vector_type(8))) short short8;
typedef __attribute__((ext_vector_type(4))) float f32x4;
typedef __attribute__((ext_vector_type(4))) unsigned short ushort4v;

template<typename T> __device__ inline float tof(T v);
template<> __device__ inline float tof<float>(float v){ return v; }
template<> __device__ inline float tof<bf16>(bf16 v){ return __bfloat162float(v); }

template<typename T> __device__ inline T fromf(float v);
template<> __device__ inline float fromf<float>(float v){ return v; }
template<> __device__ inline bf16  fromf<bf16>(float v){ return __float2bfloat16(v); }

__device__ inline unsigned short f2bf_bits(float f){
    bf16 h = __float2bfloat16(f);
    return *reinterpret_cast<unsigned short*>(&h);
}
__device__ inline float bfbits2f(unsigned short u){
    union { unsigned int i; float f; } c; c.i = ((unsigned int)u) << 16; return c.f;
}

__device__ inline float gelu_exact(float x){
    return 0.5f * x * (1.0f + erff(x * 0.70710678118654752440f));
}

// async global(16B) -> LDS
__device__ __forceinline__ void gload16(const bf16* g, bf16* l){
    __builtin_amdgcn_global_load_lds(
        (const __attribute__((address_space(1))) void*)g,
        (__attribute__((address_space(3))) void*)l, 16, 0, 0);
}

// ---------------- f32 -> bf16 flat convert -----------------------------------
__global__ __launch_bounds__(256) void conv_bf16_kernel(
    const float* __restrict__ in, bf16* __restrict__ out, int n)
{
    int i = blockIdx.x * 256 + threadIdx.x;
    if (i < n) out[i] = fromf<bf16>(in[i]);
}

// ---------------- LayerNorm over channel dim, NCHW, per pixel ----------------
__global__ __launch_bounds__(256) void ln_kernel(
    const float* __restrict__ in, const float* __restrict__ g,
    const float* __restrict__ b, float* __restrict__ out)
{
    int n = blockIdx.x * 256 + threadIdx.x;       // pixel
    int z = blockIdx.y;                           // batch
    const float* p = in  + (size_t)z * CDIM * HW + n;
    float*       q = out + (size_t)z * CDIM * HW + n;
    float s = 0.f, s2 = 0.f;
    for (int c = 0; c < CDIM; ++c){
        float v = p[(size_t)c * HW];
        s += v; s2 += v * v;
    }
    float mean = s * (1.0f / CDIM);
    float var  = s2 * (1.0f / CDIM) - mean * mean;
    float r = rsqrtf(var + 1e-5f);
    for (int c = 0; c < CDIM; ++c){
        float v = p[(size_t)c * HW];
        q[(size_t)c * HW] = (v - mean) * r * g[c] + b[c];
    }
}

// ---------------- [C][HW] (f32|bf16) -> [HW][C] bf16 transpose ---------------
template<typename T>
__global__ __launch_bounds__(256) void transpose_kernel(
    const T* __restrict__ in, bf16* __restrict__ out, int C)
{
    int z = blockIdx.z;
    int p0 = blockIdx.x * 64, c0 = blockIdx.y * 64;
    __shared__ unsigned short tile[64][66];   // [p][c], pad keeps banks spread
    const T* ib = in + (size_t)z * C * HW;
    for (int i = threadIdx.x; i < 4096; i += 256){
        int c = i >> 6, p = i & 63;           // consecutive lanes -> consecutive p
        tile[p][c] = f2bf_bits(tof<T>(ib[(size_t)(c0 + c) * HW + p0 + p]));
    }
    __syncthreads();
    unsigned short* obu = (unsigned short*)(out + (size_t)z * HW * C);
    for (int i = threadIdx.x; i < 4096; i += 256){
        int p = i >> 6, c = i & 63;           // consecutive lanes -> consecutive c
        obu[(size_t)(p0 + p) * C + c0 + c] = tile[p][c];
    }
}

// ---------------- MFMA GEMM: C[M,N] = Wb[M,K] @ XT[N,K]^T, batched -----------
// A and B staged k-contiguous in LDS with XOR-16B swizzle (both-sides).
// EPI: 0 = bf16 out [M][HW]; 1 = f32 out + residual; 2 = bias+gelu f32 out;
//      3 = bias+gelu -> transposed bf16 out [HW][M]
template<int EPI>
__global__ __launch_bounds__(256) void gemm_mfma_kernel(
    const bf16* __restrict__ Wb, const bf16* __restrict__ XT,
    void* __restrict__ Cout, const float* __restrict__ bias,
    const float* __restrict__ res, int M, int K)
{
    __shared__ bf16 smem[12288];              // A: 64x64 (4096), B: 128x64 (8192)
    bf16* Als = smem;
    bf16* Bls = smem + 4096;
    int z  = blockIdx.z;
    int n0 = blockIdx.x * 128;
    int m0 = blockIdx.y * 64;
    const bf16* Xb = XT + (size_t)z * HW * K;
    int tid  = threadIdx.x;
    int lane = tid & 63, wid = tid >> 6;
    int wm = wid & 1, wn = wid >> 1;          // 2x2 waves, each 32m x 64n
    int r16 = lane & 15, grp = lane >> 4;

    f32x4 acc[2][4];
    #pragma unroll
    for (int i = 0; i < 2; ++i)
        #pragma unroll
        for (int j = 0; j < 4; ++j){ f32x4 zz = {0.f,0.f,0.f,0.f}; acc[i][j] = zz; }

    int nkt = K >> 6;
    for (int kt = 0; kt < nkt; ++kt){
        // stage A (8KB = 512 x 16B slots), inverse-swizzled global source
        #pragma unroll
        for (int i = 0; i < 2; ++i){
            int s = i * 256 + tid;
            int row = s >> 3, ch = s & 7;
            const bf16* g = Wb + (size_t)(m0 + row) * K + kt * 64 + ((ch ^ (row & 7)) * 8);
            gload16(g, Als + s * 8);
        }
        // stage B (16KB = 1024 x 16B slots)
        #pragma unroll
        for (int i = 0; i < 4; ++i){
            int s = i * 256 + tid;
            int row = s >> 3, ch = s & 7;
            const bf16* g = Xb + (size_t)(n0 + row) * K + kt * 64 + ((ch ^ (row & 7)) * 8);
            gload16(g, Bls + s * 8);
        }
        asm volatile("s_waitcnt vmcnt(0)" ::: "memory");
        __syncthreads();
        #pragma unroll
        for (int ks = 0; ks < 2; ++ks){
            int kel = ks * 32 + grp * 8;
            short8 a[2], b[4];
            #pragma unroll
            for (int fi = 0; fi < 2; ++fi){
                int row = wm * 32 + fi * 16 + r16;
                a[fi] = *reinterpret_cast<const short8*>(Als + row * 64 + (kel ^ ((row & 7) * 8)));
            }
            #pragma unroll
            for (int fj = 0; fj < 4; ++fj){
                int row = wn * 64 + fj * 16 + r16;
                b[fj] = *reinterpret_cast<const short8*>(Bls + row * 64 + (kel ^ ((row & 7) * 8)));
            }
            #pragma unroll
            for (int fi = 0; fi < 2; ++fi)
                #pragma unroll
                for (int fj = 0; fj < 4; ++fj)
                    acc[fi][fj] = __builtin_amdgcn_mfma_f32_16x16x32_bf16(
                        a[fi], b[fj], acc[fi][fj], 0, 0, 0);
        }
        __syncthreads();
    }

    if (EPI == 3){
        // transposed bf16 store via LDS: T[n(128)][m(64)] stride 72
        unsigned short* T = (unsigned short*)smem;
        #pragma unroll
        for (int fi = 0; fi < 2; ++fi)
            #pragma unroll
            for (int fj = 0; fj < 4; ++fj){
                int nl = wn * 64 + fj * 16 + r16;
                int mb = wm * 32 + fi * 16 + grp * 4;
                #pragma unroll
                for (int rr = 0; rr < 4; ++rr){
                    float v = gelu_exact(acc[fi][fj][rr] + bias[m0 + mb + rr]);
                    T[nl * 72 + mb + rr] = f2bf_bits(v);
                }
            }
        __syncthreads();
        bf16* Y = (bf16*)Cout;
        int rrow = tid >> 1, half = tid & 1;
        const short8* srcv = reinterpret_cast<const short8*>(T + rrow * 72 + half * 32);
        short8* dstv = reinterpret_cast<short8*>(
            Y + ((size_t)z * HW + n0 + rrow) * M + m0 + half * 32);
        #pragma unroll
        for (int i = 0; i < 4; ++i) dstv[i] = srcv[i];
        return;
    }

    #pragma unroll
    for (int fi = 0; fi < 2; ++fi)
        #pragma unroll
        for (int fj = 0; fj < 4; ++fj){
            int mb = m0 + wm * 32 + fi * 16 + grp * 4;
            int n  = n0 + wn * 64 + fj * 16 + r16;
            #pragma unroll
            for (int rr = 0; rr < 4; ++rr){
                float v = acc[fi][fj][rr];
                int m = mb + rr;
                if (EPI == 0){
                    ((bf16*)Cout)[(size_t)z * M * HW + (size_t)m * HW + n] = fromf<bf16>(v);
                } else if (EPI == 1){
                    v += res[(size_t)z * M * HW + (size_t)m * HW + n];
                    ((float*)Cout)[(size_t)z * M * HW + (size_t)m * HW + n] = v;
                } else {
                    v = gelu_exact(v + bias[m]);
                    ((float*)Cout)[(size_t)z * M * HW + (size_t)m * HW + n] = v;
                }
            }
        }
}

// ---------------- depthwise 3x3, pad 1, 576 channels -------------------------
__global__ __launch_bounds__(256) void dw_kernel(
    const bf16* __restrict__ in, const float* __restrict__ wdw, bf16* __restrict__ out)
{
    int ch = blockIdx.y, z = blockIdx.z;
    int n = blockIdx.x * 256 + threadIdx.x;
    int yy = n >> 7, xx = n & 127;
    const bf16* p = in + ((size_t)z * 3 * CDIM + ch) * HW;
    float acc = 0.f;
    #pragma unroll
    for (int dy = 0; dy < 3; ++dy){
        int iy = yy + dy - 1;
        if (iy < 0 || iy >= HImg) continue;
        #pragma unroll
        for (int dx = 0; dx < 3; ++dx){
            int ix = xx + dx - 1;
            if (ix < 0 || ix >= WImg) continue;
            acc += wdw[ch * 9 + dy * 3 + dx] * tof<bf16>(p[iy * WImg + ix]);
        }
    }
    out[((size_t)z * 3 * CDIM + ch) * HW + n] = fromf<bf16>(acc);
}

// ---------------- l2-norm inverses for q and k over hw -----------------------
__global__ __launch_bounds__(256) void l2inv_kernel(
    const bf16* __restrict__ qkv, float* __restrict__ invq, float* __restrict__ invk)
{
    int bx = blockIdx.x;              // [0, 2*CDIM)
    int z  = blockIdx.y;
    int which = bx / CDIM;            // 0 = q, 1 = k
    int c     = bx % CDIM;
    const bf16* p = qkv + ((size_t)z * 3 * CDIM + which * CDIM + c) * HW;
    float s = 0.f;
    for (int i = threadIdx.x; i < HW; i += 256){
        float v = tof<bf16>(p[i]);
        s += v * v;
    }
    #pragma unroll
    for (int m = 1; m < 64; m <<= 1) s += __shfl_xor(s, m, 64);
    __shared__ float red[4];
    if ((threadIdx.x & 63) == 0) red[threadIdx.x >> 6] = s;
    __syncthreads();
    if (threadIdx.x == 0){
        float t = red[0] + red[1] + red[2] + red[3];
        float inv = 1.0f / fmaxf(sqrtf(t), 1e-12f);
        (which ? invk : invq)[z * CDIM + c] = inv;
    }
}

// ---------------- attn partials: per chunk of PCHUNK pixels ------------------
__global__ __launch_bounds__(256) void attn_qk_kernel(
    const bf16* __restrict__ qkv, const float* __restrict__ invq,
    const float* __restrict__ invk, const float* __restrict__ temp,
    float* __restrict__ part)
{
    int chunk = blockIdx.x;           // HW / PCHUNK chunks
    int h = blockIdx.y, z = blockIdx.z;
    __shared__ unsigned short qs[CP][PCHUNK + 4];
    __shared__ unsigned short ks[CP][PCHUNK + 4];
    int n0 = chunk * PCHUNK;
    const unsigned short* qb = (const unsigned short*)(qkv + ((size_t)z * 3 * CDIM + h * CP) * HW);
    const unsigned short* kb = (const unsigned short*)(qkv + ((size_t)z * 3 * CDIM + CDIM + h * CP) * HW);
    for (int i = threadIdx.x; i < CP * (PCHUNK / 4); i += 256){
        int r = i >> 6, p4 = i & 63;
        *(ushort4v*)&qs[r][p4 * 4] = *(const ushort4v*)&qb[(size_t)r * HW + n0 + p4 * 4];
        *(ushort4v*)&ks[r][p4 * 4] = *(const ushort4v*)&kb[(size_t)r * HW + n0 + p4 * 4];
    }
    __syncthreads();
    int c  = threadIdx.x >> 3;
    int d0 = (threadIdx.x & 7) * 4;
    float acc[4] = {0.f, 0.f, 0.f, 0.f};
    for (int p4 = 0; p4 < PCHUNK / 4; ++p4){
        ushort4v qv = *(const ushort4v*)&qs[c][p4 * 4];
        float qf0 = bfbits2f(qv[0]), qf1 = bfbits2f(qv[1]);
        float qf2 = bfbits2f(qv[2]), qf3 = bfbits2f(qv[3]);
        #pragma unroll
        for (int j = 0; j < 4; ++j){
            ushort4v kv = *(const ushort4v*)&ks[d0 + j][p4 * 4];
            acc[j] = fmaf(qf0, bfbits2f(kv[0]),
                     fmaf(qf1, bfbits2f(kv[1]),
                     fmaf(qf2, bfbits2f(kv[2]),
                     fmaf(qf3, bfbits2f(kv[3]), acc[j]))));
        }
    }
    float sc = invq[z * CDIM + h * CP + c] * temp[h];
    size_t base = ((size_t)chunk * BATCH * HEADS + (size_t)z * HEADS + h) * CP * CP
                + c * CP + d0;
    #pragma unroll
    for (int j = 0; j < 4; ++j)
        part[base + j] = acc[j] * sc * invk[z * CDIM + h * CP + d0 + j];
}

__global__ __launch_bounds__(256) void attn_reduce_kernel(
    const float* __restrict__ part, float* __restrict__ attn)
{
    int idx = blockIdx.x * 256 + threadIdx.x;      // < BATCH*HEADS*CP*CP
    float s = 0.f;
    for (int ch = 0; ch < HW / PCHUNK; ++ch)
        s += part[(size_t)ch * (BATCH * HEADS * CP * CP) + idx];
    attn[idx] = s;
}

// ---------------- 3x3 conv over head-channels on [HEADS, CP, CP] -------------
__global__ __launch_bounds__(256) void headconv_kernel(
    const float* __restrict__ attn, const float* __restrict__ wh, float* __restrict__ attn2)
{
    int oh = blockIdx.x, z = blockIdx.y;
    __shared__ float wsm[HEADS * 9];
    if (threadIdx.x < HEADS * 9) wsm[threadIdx.x] = wh[oh * HEADS * 9 + threadIdx.x];
    __syncthreads();
    for (int idx = threadIdx.x; idx < CP * CP; idx += 256){
        int i = idx >> 5, j = idx & 31;
        float acc = 0.f;
        for (int ih = 0; ih < HEADS; ++ih){
            const float* ab = attn + ((size_t)(z * HEADS + ih)) * CP * CP;
            #pragma unroll
            for (int dy = 0; dy < 3; ++dy){
                int ii = i + dy - 1;
                if (ii < 0 || ii >= CP) continue;
                #pragma unroll
                for (int dx = 0; dx < 3; ++dx){
                    int jj = j + dx - 1;
                    if (jj < 0 || jj >= CP) continue;
                    acc += wsm[ih * 9 + dy * 3 + dx] * ab[ii * CP + jj];
                }
            }
        }
        attn2[((size_t)(z * HEADS + oh)) * CP * CP + idx] = acc;
    }
}

// ---------------- softmax over last dim (32) ---------------------------------
__global__ __launch_bounds__(1024) void softmax_kernel(float* __restrict__ attn2)
{
    int h = blockIdx.x, z = blockIdx.y;
    float* p = attn2 + ((size_t)(z * HEADS + h)) * CP * CP;
    int r = threadIdx.x >> 5, j = threadIdx.x & 31;
    float v = p[r * CP + j];
    float mx = v;
    #pragma unroll
    for (int m = 1; m < 32; m <<= 1) mx = fmaxf(mx, __shfl_xor(mx, m, 32));
    float e = expf(v - mx);
    float sum = e;
    #pragma unroll
    for (int m = 1; m < 32; m <<= 1) sum += __shfl_xor(sum, m, 32);
    p[r * CP + j] = e / sum;
}

// ---------------- out = attn2 @ v  (bf16 out) --------------------------------
__global__ __launch_bounds__(256) void av_kernel(
    const float* __restrict__ attn2, const bf16* __restrict__ qkv, bf16* __restrict__ out)
{
    int h = blockIdx.y, z = blockIdx.z;
    int n = blockIdx.x * 256 + threadIdx.x;
    __shared__ float As[CP][CP];
    for (int i = threadIdx.x; i < CP * CP; i += 256)
        As[i >> 5][i & 31] = attn2[((size_t)(z * HEADS + h)) * CP * CP + i];
    __syncthreads();
    const bf16* vb = qkv + ((size_t)z * 3 * CDIM + 2 * CDIM + h * CP) * HW + n;
    float vreg[CP];
    #pragma unroll
    for (int d = 0; d < CP; ++d) vreg[d] = tof<bf16>(vb[(size_t)d * HW]);
    bf16* ob = out + ((size_t)z * CDIM + h * CP) * HW + n;
    for (int c = 0; c < CP; ++c){
        float acc = 0.f;
        #pragma unroll
        for (int d = 0; d < CP; ++d) acc = fmaf(As[c][d], vreg[d], acc);
        ob[(size_t)c * HW] = fromf<bf16>(acc);
    }
}

// ---------------- spatial gate: sigmoid(conv3x3(y, 192->1)) ------------------
__global__ __launch_bounds__(256) void gate_kernel(
    const float* __restrict__ y, const float* __restrict__ wsa,
    const float* __restrict__ bsa, float* __restrict__ gate)
{
    __shared__ float wsm[CDIM * 9];
    for (int i = threadIdx.x; i < CDIM * 9; i += 256) wsm[i] = wsa[i];
    __syncthreads();
    int z = blockIdx.y;
    int n = blockIdx.x * 256 + threadIdx.x;
    int yy = n >> 7, xx = n & 127;
    const float* yb = y + (size_t)z * CDIM * HW;
    float acc = bsa[0];
    for (int c = 0; c < CDIM; ++c){
        const float* pc = yb + (size_t)c * HW;
        #pragma unroll
        for (int dy = 0; dy < 3; ++dy){
            int iy = yy + dy - 1;
            if (iy < 0 || iy >= HImg) continue;
            #pragma unroll
            for (int dx = 0; dx < 3; ++dx){
                int ix = xx + dx - 1;
                if (ix < 0 || ix >= WImg) continue;
                acc += wsm[c * 9 + dy * 3 + dx] * pc[iy * WImg + ix];
            }
        }
    }
    gate[(size_t)z * HW + n] = 1.0f / (1.0f + expf(-acc));
}

// ---------------- final: out = x2 + y2 * gate --------------------------------
__global__ __launch_bounds__(256) void final_kernel(
    const float* __restrict__ x2, const float* __restrict__ y2,
    const float* __restrict__ gate, float* __restrict__ out)
{
    size_t idx = (size_t)blockIdx.x * 256 + threadIdx.x;
    int n = (int)(idx % HW);
    int z = (int)(idx / ((size_t)CDIM * HW));
    out[idx] = x2[idx] + y2[idx] * gate[(size_t)z * HW + n];
}

extern "C" void kernel_launch(void* const* d_in, const int* in_sizes, int n_in,
                              void* d_out, int out_size, void* d_ws, size_t ws_size,
                              hipStream_t stream)
{
    const float* x      = (const float*)d_in[0];
    const float* g1     = (const float*)d_in[1];
    const float* b1     = (const float*)d_in[2];
    const float* w_qkv  = (const float*)d_in[3];
    const float* w_dw   = (const float*)d_in[4];
    const float* temp   = (const float*)d_in[5];
    const float* w_head = (const float*)d_in[6];
    const float* w_proj = (const float*)d_in[7];
    const float* g2     = (const float*)d_in[8];
    const float* b2     = (const float*)d_in[9];
    const float* w_fc1  = (const float*)d_in[10];
    const float* b_fc1  = (const float*)d_in[11];
    const float* w_fc2  = (const float*)d_in[12];
    const float* b_fc2  = (const float*)d_in[13];
    const float* w_sa   = (const float*)d_in[14];
    const float* b_sa   = (const float*)d_in[15];
    float* out = (float*)d_out;

    char* ws = (char*)d_ws;
    const size_t FULL = (size_t)BATCH * CDIM * HW;      // 12.58M elems

    // R0: FULL f32  (x1 -> ln2 -> y2)
    float* x1  = (float*)ws;
    float* ln2 = x1;
    float* y2  = x1;
    // R1: 3*FULL bf16 (qkv) -> {attn_out bf16, attn_outT bf16} -> y1T bf16 (2*FULL)
    char* R1 = ws + FULL * 4;
    bf16*  qkvA      = (bf16*)R1;
    bf16*  attn_out  = (bf16*)R1;
    bf16*  attn_outT = (bf16*)(R1 + FULL * 2);
    bf16*  y1T       = (bf16*)R1;
    // R2: {x1T bf16} -> 3*FULL bf16 (dw qkv) -> {x2 f32 (FULL*4B), ln2T bf16 at +FULL*4}
    char* R2 = R1 + FULL * 3 * 2;
    bf16*  x1T  = (bf16*)R2;
    bf16*  dwB  = (bf16*)R2;
    float* x2   = (float*)R2;
    bf16*  ln2T = (bf16*)(R2 + FULL * 4);
    // small region
    char* SM = R2 + FULL * 3 * 2;
    float* invq  = (float*)SM;                              // B*CDIM
    float* invk  = invq + BATCH * CDIM;
    float* attn  = invk + BATCH * CDIM;                     // B*HEADS*CP*CP
    float* attn2 = attn + BATCH * HEADS * CP * CP;
    float* gate  = attn2 + BATCH * HEADS * CP * CP;         // B*HW
    float* part  = gate + BATCH * HW;                       // 64*B*HEADS*CP*CP
    bf16* wq_b  = (bf16*)(part + (HW / PCHUNK) * BATCH * HEADS * CP * CP);
    bf16* wp_b  = wq_b  + 576 * 192;
    bf16* wf1_b = wp_b  + 192 * 192;
    bf16* wf2_b = wf1_b + 384 * 192;

    dim3 blk(256);

    // 0. weight conversions to bf16
    conv_bf16_kernel<<<dim3((576*192 + 255)/256), blk, 0, stream>>>(w_qkv,  wq_b,  576*192);
    conv_bf16_kernel<<<dim3((192*192 + 255)/256), blk, 0, stream>>>(w_proj, wp_b,  192*192);
    conv_bf16_kernel<<<dim3((384*192 + 255)/256), blk, 0, stream>>>(w_fc1,  wf1_b, 384*192);
    conv_bf16_kernel<<<dim3((192*384 + 255)/256), blk, 0, stream>>>(w_fc2,  wf2_b, 192*384);
    // 1. LayerNorm1 (residual uses normed x per reference)
    ln_kernel<<<dim3(HW / 256, BATCH), blk, 0, stream>>>(x, g1, b1, x1);
    // 1.5 transpose x1 -> x1T bf16 [HW][C]
    transpose_kernel<float><<<dim3(HW / 64, CDIM / 64, BATCH), blk, 0, stream>>>(x1, x1T, CDIM);
    // 2. qkv GEMM (576 x 16384 x 192) -> bf16 [3C][HW]
    gemm_mfma_kernel<0><<<dim3(HW / 128, (3 * CDIM) / 64, BATCH), blk, 0, stream>>>(
        wq_b, x1T, qkvA, nullptr, nullptr, 3 * CDIM, CDIM);
    // 3. depthwise 3x3
    dw_kernel<<<dim3(HW / 256, 3 * CDIM, BATCH), blk, 0, stream>>>(qkvA, w_dw, dwB);
    // 4. l2 norm inverses for q,k
    l2inv_kernel<<<dim3(2 * CDIM, BATCH), blk, 0, stream>>>(dwB, invq, invk);
    // 5. attn partial dot-products over pixel chunks
    attn_qk_kernel<<<dim3(HW / PCHUNK, HEADS, BATCH), blk, 0, stream>>>(
        dwB, invq, invk, temp, part);
    // 6. deterministic reduction of partials
    attn_reduce_kernel<<<dim3((BATCH * HEADS * CP * CP) / 256), blk, 0, stream>>>(part, attn);
    // 7. 3x3 conv over head channels
    headconv_kernel<<<dim3(HEADS, BATCH), blk, 0, stream>>>(attn, w_head, attn2);
    // 8. softmax over last dim
    softmax_kernel<<<dim3(HEADS, BATCH), dim3(1024), 0, stream>>>(attn2);
    // 9. out = attn @ v -> bf16 [C][HW]
    av_kernel<<<dim3(HW / 256, HEADS, BATCH), blk, 0, stream>>>(attn2, dwB, attn_out);
    // 9.5 transpose attn_out -> attn_outT bf16 [HW][C]
    transpose_kernel<bf16><<<dim3(HW / 64, CDIM / 64, BATCH), blk, 0, stream>>>(
        attn_out, attn_outT, CDIM);
    // 10. proj GEMM + residual(x1) -> x2 f32 [C][HW]
    gemm_mfma_kernel<1><<<dim3(HW / 128, CDIM / 64, BATCH), blk, 0, stream>>>(
        wp_b, attn_outT, x2, nullptr, x1, CDIM, CDIM);
    // 11. LayerNorm2
    ln_kernel<<<dim3(HW / 256, BATCH), blk, 0, stream>>>(x2, g2, b2, ln2);
    // 11.5 transpose ln2 -> ln2T bf16 [HW][C]
    transpose_kernel<float><<<dim3(HW / 64, CDIM / 64, BATCH), blk, 0, stream>>>(ln2, ln2T, CDIM);
    // 12. fc1 GEMM + bias + gelu -> y1T bf16 [HW][HIDDEN]
    gemm_mfma_kernel<3><<<dim3(HW / 128, HIDDEN / 64, BATCH), blk, 0, stream>>>(
        wf1_b, ln2T, y1T, b_fc1, nullptr, HIDDEN, CDIM);
    // 13. fc2 GEMM + bias + gelu -> y2 f32 [C][HW]
    gemm_mfma_kernel<2><<<dim3(HW / 128, CDIM / 64, BATCH), blk, 0, stream>>>(
        wf2_b, y1T, y2, b_fc2, nullptr, CDIM, HIDDEN);
    // 14. spatial gate
    gate_kernel<<<dim3(HW / 256, BATCH), blk, 0, stream>>>(y2, w_sa, b_sa, gate);
    // 15. final: out = x2 + y2*gate
    final_kernel<<<dim3((int)(FULL / 256)), blk, 0, stream>>>(x2, y2, gate, out);
}

// Round 3
// 558.125 us; speedup vs baseline: 2.5753x; 1.4151x over previous
//
#include <hip/hip_runtime.h>
#include <hip/hip_bf16.h>
#include <math.h>

using bf16 = __hip_bfloat16;

static constexpr int CDIM   = 192;
static constexpr int HEADS  = 6;
static constexpr int CP     = 32;     // CDIM / HEADS
static constexpr int HIDDEN = 384;
static constexpr int HImg   = 128;
static constexpr int WImg   = 128;
static constexpr int HW     = HImg * WImg;   // 16384
static constexpr int BATCH  = 4;
static constexpr int PCHUNK = 256;    // attn contraction chunk
static constexpr int CSPLIT = 12;     // gate conv channel splits (16 ch each)

typedef __attribute__((ext_vector_type(8))) short short8;
typedef __attribute__((ext_vector_type(4))) float f32x4;
typedef __attribute__((ext_vector_type(4))) unsigned short ushort4v;

template<typename T> __device__ inline float tof(T v);
template<> __device__ inline float tof<float>(float v){ return v; }
template<> __device__ inline float tof<bf16>(bf16 v){ return __bfloat162float(v); }

template<typename T> __device__ inline T fromf(float v);
template<> __device__ inline float fromf<float>(float v){ return v; }
template<> __device__ inline bf16  fromf<bf16>(float v){ return __float2bfloat16(v); }

__device__ inline unsigned short f2bf_bits(float f){
    bf16 h = __float2bfloat16(f);
    return *reinterpret_cast<unsigned short*>(&h);
}
__device__ inline float bfbits2f(unsigned short u){
    union { unsigned int i; float f; } c; c.i = ((unsigned int)u) << 16; return c.f;
}

__device__ inline float gelu_exact(float x){
    return 0.5f * x * (1.0f + erff(x * 0.70710678118654752440f));
}

// async global(16B) -> LDS
__device__ __forceinline__ void gload16(const bf16* g, bf16* l){
    __builtin_amdgcn_global_load_lds(
        (const __attribute__((address_space(1))) void*)g,
        (__attribute__((address_space(3))) void*)l, 16, 0, 0);
}

// ---------------- merged f32 -> bf16 weight convert --------------------------
__global__ __launch_bounds__(256) void convw_kernel(
    const float* __restrict__ w_qkv, const float* __restrict__ w_proj,
    const float* __restrict__ w_fc1, const float* __restrict__ w_fc2,
    bf16* __restrict__ wq, bf16* __restrict__ wp,
    bf16* __restrict__ wf1, bf16* __restrict__ wf2)
{
    int i = blockIdx.x * 256 + threadIdx.x;
    const int n0 = 576*192, n1 = n0 + 192*192, n2 = n1 + 384*192, n3 = n2 + 192*384;
    if (i < n0)      wq[i]       = fromf<bf16>(w_qkv[i]);
    else if (i < n1) wp[i - n0]  = fromf<bf16>(w_proj[i - n0]);
    else if (i < n2) wf1[i - n1] = fromf<bf16>(w_fc1[i - n1]);
    else if (i < n3) wf2[i - n2] = fromf<bf16>(w_fc2[i - n2]);
}

// ---------------- fused LayerNorm (+optional f32 out) + bf16 transpose -------
// in: f32 [C][HW]; outT: bf16 [HW][C]; outF (if WF32): f32 [C][HW]
template<bool WF32>
__global__ __launch_bounds__(256) void ln_fused_kernel(
    const float* __restrict__ in, const float* __restrict__ g,
    const float* __restrict__ b, float* __restrict__ outF, bf16* __restrict__ outT)
{
    int z = blockIdx.y, p0 = blockIdx.x * 64;
    __shared__ float tile[CDIM][65];
    __shared__ float sred[4][64], s2red[4][64];
    __shared__ float mrow[64], rrow[64];
    const float* ib = in + (size_t)z * CDIM * HW + p0;
    int tid = threadIdx.x;
    // load 192 x 64 f32 tile (float4 per lane, coalesced)
    for (int j = tid; j < CDIM * 16; j += 256){
        int c = j >> 4, p4 = (j & 15) * 4;
        f32x4 v = *reinterpret_cast<const f32x4*>(ib + (size_t)c * HW + p4);
        tile[c][p4]   = v[0]; tile[c][p4+1] = v[1];
        tile[c][p4+2] = v[2]; tile[c][p4+3] = v[3];
    }
    __syncthreads();
    int p = tid & 63, q = tid >> 6;
    float s = 0.f, s2 = 0.f;
    #pragma unroll 4
    for (int c = q * 48; c < q * 48 + 48; ++c){
        float v = tile[c][p]; s += v; s2 += v * v;
    }
    sred[q][p] = s; s2red[q][p] = s2;
    __syncthreads();
    if (tid < 64){
        float ts = sred[0][tid] + sred[1][tid] + sred[2][tid] + sred[3][tid];
        float t2 = s2red[0][tid] + s2red[1][tid] + s2red[2][tid] + s2red[3][tid];
        float mean = ts * (1.0f / CDIM);
        float var  = t2 * (1.0f / CDIM) - mean * mean;
        mrow[tid] = mean;
        rrow[tid] = rsqrtf(var + 1e-5f);
    }
    __syncthreads();
    // transposed bf16 out [HW][C]
    unsigned short* oT = (unsigned short*)(outT + ((size_t)z * HW + p0) * CDIM);
    for (int j = tid; j < 64 * 48; j += 256){
        int pr = j / 48, c4 = (j % 48) * 4;
        float m = mrow[pr], r = rrow[pr];
        ushort4v o;
        #pragma unroll
        for (int k = 0; k < 4; ++k){
            int c = c4 + k;
            o[k] = f2bf_bits((tile[c][pr] - m) * r * g[c] + b[c]);
        }
        *(ushort4v*)&oT[(size_t)pr * CDIM + c4] = o;
    }
    if (WF32){
        float* oF = outF + (size_t)z * CDIM * HW + p0;
        for (int j = tid; j < CDIM * 16; j += 256){
            int c = j >> 4, p4 = (j & 15) * 4;
            float gg = g[c], bb = b[c];
            f32x4 v;
            #pragma unroll
            for (int k = 0; k < 4; ++k)
                v[k] = (tile[c][p4 + k] - mrow[p4 + k]) * rrow[p4 + k] * gg + bb;
            *reinterpret_cast<f32x4*>(oF + (size_t)c * HW + p4) = v;
        }
    }
}

// ---------------- MFMA GEMM: C[M,N] = Wb[M,K] @ XT[N,K]^T, batched -----------
// EPI: 0 = bf16 out [M][HW]; 1 = f32 out + residual; 2 = bias+gelu f32 out;
//      3 = bias+gelu -> transposed bf16 out [HW][M]
template<int EPI>
__global__ __launch_bounds__(256) void gemm_mfma_kernel(
    const bf16* __restrict__ Wb, const bf16* __restrict__ XT,
    void* __restrict__ Cout, const float* __restrict__ bias,
    const float* __restrict__ res, int M, int K)
{
    __shared__ bf16 smem[12288];              // A: 64x64 (4096), B: 128x64 (8192)
    bf16* Als = smem;
    bf16* Bls = smem + 4096;
    int z  = blockIdx.z;
    int n0 = blockIdx.x * 128;
    int m0 = blockIdx.y * 64;
    const bf16* Xb = XT + (size_t)z * HW * K;
    int tid  = threadIdx.x;
    int lane = tid & 63, wid = tid >> 6;
    int wm = wid & 1, wn = wid >> 1;          // 2x2 waves, each 32m x 64n
    int r16 = lane & 15, grp = lane >> 4;

    f32x4 acc[2][4];
    #pragma unroll
    for (int i = 0; i < 2; ++i)
        #pragma unroll
        for (int j = 0; j < 4; ++j){ f32x4 zz = {0.f,0.f,0.f,0.f}; acc[i][j] = zz; }

    int nkt = K >> 6;
    for (int kt = 0; kt < nkt; ++kt){
        #pragma unroll
        for (int i = 0; i < 2; ++i){
            int s = i * 256 + tid;
            int row = s >> 3, ch = s & 7;
            const bf16* g = Wb + (size_t)(m0 + row) * K + kt * 64 + ((ch ^ (row & 7)) * 8);
            gload16(g, Als + s * 8);
        }
        #pragma unroll
        for (int i = 0; i < 4; ++i){
            int s = i * 256 + tid;
            int row = s >> 3, ch = s & 7;
            const bf16* g = Xb + (size_t)(n0 + row) * K + kt * 64 + ((ch ^ (row & 7)) * 8);
            gload16(g, Bls + s * 8);
        }
        asm volatile("s_waitcnt vmcnt(0)" ::: "memory");
        __syncthreads();
        #pragma unroll
        for (int ks = 0; ks < 2; ++ks){
            int kel = ks * 32 + grp * 8;
            short8 a[2], b[4];
            #pragma unroll
            for (int fi = 0; fi < 2; ++fi){
                int row = wm * 32 + fi * 16 + r16;
                a[fi] = *reinterpret_cast<const short8*>(Als + row * 64 + (kel ^ ((row & 7) * 8)));
            }
            #pragma unroll
            for (int fj = 0; fj < 4; ++fj){
                int row = wn * 64 + fj * 16 + r16;
                b[fj] = *reinterpret_cast<const short8*>(Bls + row * 64 + (kel ^ ((row & 7) * 8)));
            }
            #pragma unroll
            for (int fi = 0; fi < 2; ++fi)
                #pragma unroll
                for (int fj = 0; fj < 4; ++fj)
                    acc[fi][fj] = __builtin_amdgcn_mfma_f32_16x16x32_bf16(
                        a[fi], b[fj], acc[fi][fj], 0, 0, 0);
        }
        __syncthreads();
    }

    if (EPI == 3){
        unsigned short* T = (unsigned short*)smem;
        #pragma unroll
        for (int fi = 0; fi < 2; ++fi)
            #pragma unroll
            for (int fj = 0; fj < 4; ++fj){
                int nl = wn * 64 + fj * 16 + r16;
                int mb = wm * 32 + fi * 16 + grp * 4;
                #pragma unroll
                for (int rr = 0; rr < 4; ++rr){
                    float v = gelu_exact(acc[fi][fj][rr] + bias[m0 + mb + rr]);
                    T[nl * 72 + mb + rr] = f2bf_bits(v);
                }
            }
        __syncthreads();
        bf16* Y = (bf16*)Cout;
        int rrow = tid >> 1, half = tid & 1;
        const short8* srcv = reinterpret_cast<const short8*>(T + rrow * 72 + half * 32);
        short8* dstv = reinterpret_cast<short8*>(
            Y + ((size_t)z * HW + n0 + rrow) * M + m0 + half * 32);
        #pragma unroll
        for (int i = 0; i < 4; ++i) dstv[i] = srcv[i];
        return;
    }

    #pragma unroll
    for (int fi = 0; fi < 2; ++fi)
        #pragma unroll
        for (int fj = 0; fj < 4; ++fj){
            int mb = m0 + wm * 32 + fi * 16 + grp * 4;
            int n  = n0 + wn * 64 + fj * 16 + r16;
            #pragma unroll
            for (int rr = 0; rr < 4; ++rr){
                float v = acc[fi][fj][rr];
                int m = mb + rr;
                if (EPI == 0){
                    ((bf16*)Cout)[(size_t)z * M * HW + (size_t)m * HW + n] = fromf<bf16>(v);
                } else if (EPI == 1){
                    v += res[(size_t)z * M * HW + (size_t)m * HW + n];
                    ((float*)Cout)[(size_t)z * M * HW + (size_t)m * HW + n] = v;
                } else {
                    v = gelu_exact(v + bias[m]);
                    ((float*)Cout)[(size_t)z * M * HW + (size_t)m * HW + n] = v;
                }
            }
        }
}

// ---------------- depthwise 3x3, pad 1, 576 channels -------------------------
__global__ __launch_bounds__(256) void dw_kernel(
    const bf16* __restrict__ in, const float* __restrict__ wdw, bf16* __restrict__ out)
{
    int ch = blockIdx.y, z = blockIdx.z;
    int n = blockIdx.x * 256 + threadIdx.x;
    int yy = n >> 7, xx = n & 127;
    const bf16* p = in + ((size_t)z * 3 * CDIM + ch) * HW;
    float acc = 0.f;
    #pragma unroll
    for (int dy = 0; dy < 3; ++dy){
        int iy = yy + dy - 1;
        if (iy < 0 || iy >= HImg) continue;
        #pragma unroll
        for (int dx = 0; dx < 3; ++dx){
            int ix = xx + dx - 1;
            if (ix < 0 || ix >= WImg) continue;
            acc += wdw[ch * 9 + dy * 3 + dx] * tof<bf16>(p[iy * WImg + ix]);
        }
    }
    out[((size_t)z * 3 * CDIM + ch) * HW + n] = fromf<bf16>(acc);
}

// ---------------- l2-norm inverses for q and k over hw -----------------------
__global__ __launch_bounds__(256) void l2inv_kernel(
    const bf16* __restrict__ qkv, float* __restrict__ invq, float* __restrict__ invk)
{
    int bx = blockIdx.x;              // [0, 2*CDIM)
    int z  = blockIdx.y;
    int which = bx / CDIM;            // 0 = q, 1 = k
    int c     = bx % CDIM;
    const bf16* p = qkv + ((size_t)z * 3 * CDIM + which * CDIM + c) * HW;
    float s = 0.f;
    for (int i = threadIdx.x; i < HW; i += 256){
        float v = tof<bf16>(p[i]);
        s += v * v;
    }
    #pragma unroll
    for (int m = 1; m < 64; m <<= 1) s += __shfl_xor(s, m, 64);
    __shared__ float red[4];
    if ((threadIdx.x & 63) == 0) red[threadIdx.x >> 6] = s;
    __syncthreads();
    if (threadIdx.x == 0){
        float t = red[0] + red[1] + red[2] + red[3];
        float inv = 1.0f / fmaxf(sqrtf(t), 1e-12f);
        (which ? invk : invq)[z * CDIM + c] = inv;
    }
}

// ---------------- attn partials: per chunk of PCHUNK pixels ------------------
__global__ __launch_bounds__(256) void attn_qk_kernel(
    const bf16* __restrict__ qkv, const float* __restrict__ invq,
    const float* __restrict__ invk, const float* __restrict__ temp,
    float* __restrict__ part)
{
    int chunk = blockIdx.x;           // HW / PCHUNK chunks
    int h = blockIdx.y, z = blockIdx.z;
    __shared__ unsigned short qs[CP][PCHUNK + 4];
    __shared__ unsigned short ks[CP][PCHUNK + 4];
    int n0 = chunk * PCHUNK;
    const unsigned short* qb = (const unsigned short*)(qkv + ((size_t)z * 3 * CDIM + h * CP) * HW);
    const unsigned short* kb = (const unsigned short*)(qkv + ((size_t)z * 3 * CDIM + CDIM + h * CP) * HW);
    for (int i = threadIdx.x; i < CP * (PCHUNK / 4); i += 256){
        int r = i >> 6, p4 = i & 63;
        *(ushort4v*)&qs[r][p4 * 4] = *(const ushort4v*)&qb[(size_t)r * HW + n0 + p4 * 4];
        *(ushort4v*)&ks[r][p4 * 4] = *(const ushort4v*)&kb[(size_t)r * HW + n0 + p4 * 4];
    }
    __syncthreads();
    int c  = threadIdx.x >> 3;
    int d0 = (threadIdx.x & 7) * 4;
    float acc[4] = {0.f, 0.f, 0.f, 0.f};
    for (int p4 = 0; p4 < PCHUNK / 4; ++p4){
        ushort4v qv = *(const ushort4v*)&qs[c][p4 * 4];
        float qf0 = bfbits2f(qv[0]), qf1 = bfbits2f(qv[1]);
        float qf2 = bfbits2f(qv[2]), qf3 = bfbits2f(qv[3]);
        #pragma unroll
        for (int j = 0; j < 4; ++j){
            ushort4v kv = *(const ushort4v*)&ks[d0 + j][p4 * 4];
            acc[j] = fmaf(qf0, bfbits2f(kv[0]),
                     fmaf(qf1, bfbits2f(kv[1]),
                     fmaf(qf2, bfbits2f(kv[2]),
                     fmaf(qf3, bfbits2f(kv[3]), acc[j]))));
        }
    }
    float sc = invq[z * CDIM + h * CP + c] * temp[h];
    size_t base = ((size_t)chunk * BATCH * HEADS + (size_t)z * HEADS + h) * CP * CP
                + c * CP + d0;
    #pragma unroll
    for (int j = 0; j < 4; ++j)
        part[base + j] = acc[j] * sc * invk[z * CDIM + h * CP + d0 + j];
}

__global__ __launch_bounds__(256) void attn_reduce_kernel(
    const float* __restrict__ part, float* __restrict__ attn)
{
    int idx = blockIdx.x * 256 + threadIdx.x;      // < BATCH*HEADS*CP*CP
    float s = 0.f;
    for (int ch = 0; ch < HW / PCHUNK; ++ch)
        s += part[(size_t)ch * (BATCH * HEADS * CP * CP) + idx];
    attn[idx] = s;
}

// ---------------- 3x3 conv over head-channels on [HEADS, CP, CP] -------------
__global__ __launch_bounds__(256) void headconv_kernel(
    const float* __restrict__ attn, const float* __restrict__ wh, float* __restrict__ attn2)
{
    int oh = blockIdx.x, z = blockIdx.y;
    __shared__ float wsm[HEADS * 9];
    if (threadIdx.x < HEADS * 9) wsm[threadIdx.x] = wh[oh * HEADS * 9 + threadIdx.x];
    __syncthreads();
    for (int idx = threadIdx.x; idx < CP * CP; idx += 256){
        int i = idx >> 5, j = idx & 31;
        float acc = 0.f;
        for (int ih = 0; ih < HEADS; ++ih){
            const float* ab = attn + ((size_t)(z * HEADS + ih)) * CP * CP;
            #pragma unroll
            for (int dy = 0; dy < 3; ++dy){
                int ii = i + dy - 1;
                if (ii < 0 || ii >= CP) continue;
                #pragma unroll
                for (int dx = 0; dx < 3; ++dx){
                    int jj = j + dx - 1;
                    if (jj < 0 || jj >= CP) continue;
                    acc += wsm[ih * 9 + dy * 3 + dx] * ab[ii * CP + jj];
                }
            }
        }
        attn2[((size_t)(z * HEADS + oh)) * CP * CP + idx] = acc;
    }
}

// ---------------- softmax over last dim (32) ---------------------------------
__global__ __launch_bounds__(1024) void softmax_kernel(float* __restrict__ attn2)
{
    int h = blockIdx.x, z = blockIdx.y;
    float* p = attn2 + ((size_t)(z * HEADS + h)) * CP * CP;
    int r = threadIdx.x >> 5, j = threadIdx.x & 31;
    float v = p[r * CP + j];
    float mx = v;
    #pragma unroll
    for (int m = 1; m < 32; m <<= 1) mx = fmaxf(mx, __shfl_xor(mx, m, 32));
    float e = expf(v - mx);
    float sum = e;
    #pragma unroll
    for (int m = 1; m < 32; m <<= 1) sum += __shfl_xor(sum, m, 32);
    p[r * CP + j] = e / sum;
}

// ---------------- out = attn2 @ v -> transposed bf16 [HW][C] -----------------
__global__ __launch_bounds__(256) void av_kernel(
    const float* __restrict__ attn2, const bf16* __restrict__ qkv, bf16* __restrict__ outT)
{
    int h = blockIdx.y, z = blockIdx.z;
    int tid = threadIdx.x;
    int n = blockIdx.x * 256 + tid;
    __shared__ float As[CP][CP];
    __shared__ unsigned short ot[256][36];
    for (int i = tid; i < CP * CP; i += 256)
        As[i >> 5][i & 31] = attn2[((size_t)(z * HEADS + h)) * CP * CP + i];
    __syncthreads();
    const bf16* vb = qkv + ((size_t)z * 3 * CDIM + 2 * CDIM + h * CP) * HW + n;
    float vreg[CP];
    #pragma unroll
    for (int d = 0; d < CP; ++d) vreg[d] = tof<bf16>(vb[(size_t)d * HW]);
    for (int c = 0; c < CP; ++c){
        float acc = 0.f;
        #pragma unroll
        for (int d = 0; d < CP; ++d) acc = fmaf(As[c][d], vreg[d], acc);
        ot[tid][c] = f2bf_bits(acc);
    }
    __syncthreads();
    unsigned short* ob = (unsigned short*)outT
        + ((size_t)z * HW + (size_t)blockIdx.x * 256) * CDIM + h * CP;
    for (int j = tid; j < 256 * 8; j += 256){
        int row = j >> 3, q4 = (j & 7) * 4;
        *(ushort4v*)&ob[(size_t)row * CDIM + q4] = *(ushort4v*)&ot[row][q4];
    }
}

// ---------------- spatial gate partials (16 channels per block) --------------
__global__ __launch_bounds__(256) void gate_partial_kernel(
    const float* __restrict__ y, const float* __restrict__ wsa,
    float* __restrict__ part_g)
{
    int cs = blockIdx.y, z = blockIdx.z;
    __shared__ float wsm[16 * 9];
    if (threadIdx.x < 144) wsm[threadIdx.x] = wsa[cs * 144 + threadIdx.x];
    __syncthreads();
    int n = blockIdx.x * 256 + threadIdx.x;
    int yy = n >> 7, xx = n & 127;
    const float* yb = y + (size_t)z * CDIM * HW + (size_t)cs * 16 * HW;
    float acc = 0.f;
    for (int c = 0; c < 16; ++c){
        const float* pc = yb + (size_t)c * HW;
        #pragma unroll
        for (int dy = 0; dy < 3; ++dy){
            int iy = yy + dy - 1;
            if (iy < 0 || iy >= HImg) continue;
            #pragma unroll
            for (int dx = 0; dx < 3; ++dx){
                int ix = xx + dx - 1;
                if (ix < 0 || ix >= WImg) continue;
                acc += wsm[c * 9 + dy * 3 + dx] * pc[iy * WImg + ix];
            }
        }
    }
    part_g[((size_t)cs * BATCH + z) * HW + n] = acc;
}

__global__ __launch_bounds__(256) void gate_finish_kernel(
    const float* __restrict__ part_g, const float* __restrict__ bsa,
    float* __restrict__ gate)
{
    int idx = blockIdx.x * 256 + threadIdx.x;      // < BATCH*HW
    float acc = bsa[0];
    #pragma unroll
    for (int cs = 0; cs < CSPLIT; ++cs)
        acc += part_g[(size_t)cs * BATCH * HW + idx];
    gate[idx] = 1.0f / (1.0f + expf(-acc));
}

// ---------------- final: out = x2 + y2 * gate --------------------------------
__global__ __launch_bounds__(256) void final_kernel(
    const float* __restrict__ x2, const float* __restrict__ y2,
    const float* __restrict__ gate, float* __restrict__ out)
{
    size_t idx = (size_t)blockIdx.x * 256 + threadIdx.x;
    int n = (int)(idx % HW);
    int z = (int)(idx / ((size_t)CDIM * HW));
    out[idx] = x2[idx] + y2[idx] * gate[(size_t)z * HW + n];
}

extern "C" void kernel_launch(void* const* d_in, const int* in_sizes, int n_in,
                              void* d_out, int out_size, void* d_ws, size_t ws_size,
                              hipStream_t stream)
{
    const float* x      = (const float*)d_in[0];
    const float* g1     = (const float*)d_in[1];
    const float* b1     = (const float*)d_in[2];
    const float* w_qkv  = (const float*)d_in[3];
    const float* w_dw   = (const float*)d_in[4];
    const float* temp   = (const float*)d_in[5];
    const float* w_head = (const float*)d_in[6];
    const float* w_proj = (const float*)d_in[7];
    const float* g2     = (const float*)d_in[8];
    const float* b2     = (const float*)d_in[9];
    const float* w_fc1  = (const float*)d_in[10];
    const float* b_fc1  = (const float*)d_in[11];
    const float* w_fc2  = (const float*)d_in[12];
    const float* b_fc2  = (const float*)d_in[13];
    const float* w_sa   = (const float*)d_in[14];
    const float* b_sa   = (const float*)d_in[15];
    float* out = (float*)d_out;

    char* ws = (char*)d_ws;
    const size_t FULL = (size_t)BATCH * CDIM * HW;      // 12.58M elems

    // R0: FULL f32  (x1 -> y2)
    float* x1 = (float*)ws;
    float* y2 = x1;
    // R1 (6F bytes): qkvA bf16 3FULL -> attn_outT bf16 -> {ln2T bf16 | y1T bf16}
    char* R1 = ws + FULL * 4;
    bf16*  qkvA      = (bf16*)R1;
    bf16*  attn_outT = (bf16*)R1;
    bf16*  ln2T      = (bf16*)R1;
    bf16*  y1T       = (bf16*)(R1 + FULL * 2);
    // R2 (6F bytes): x1T bf16 -> dwB bf16 3FULL -> x2 f32
    char* R2 = R1 + FULL * 3 * 2;
    bf16*  x1T = (bf16*)R2;
    bf16*  dwB = (bf16*)R2;
    float* x2  = (float*)R2;
    // small region
    char* SM = R2 + FULL * 3 * 2;
    float* invq  = (float*)SM;                              // B*CDIM
    float* invk  = invq + BATCH * CDIM;
    float* attn  = invk + BATCH * CDIM;                     // B*HEADS*CP*CP
    float* attn2 = attn + BATCH * HEADS * CP * CP;
    float* gate  = attn2 + BATCH * HEADS * CP * CP;         // B*HW
    float* part  = gate + BATCH * HW;                       // 64*B*HEADS*CP*CP (6.3MB)
    float* part_g = part;                                   // aliases part (dead by then)
    bf16* wq_b  = (bf16*)(part + (HW / PCHUNK) * BATCH * HEADS * CP * CP);
    bf16* wp_b  = wq_b  + 576 * 192;
    bf16* wf1_b = wp_b  + 192 * 192;
    bf16* wf2_b = wf1_b + 384 * 192;

    dim3 blk(256);

    // 0. merged weight conversion to bf16
    convw_kernel<<<dim3((294912 + 255) / 256), blk, 0, stream>>>(
        w_qkv, w_proj, w_fc1, w_fc2, wq_b, wp_b, wf1_b, wf2_b);
    // 1. LayerNorm1 fused: x -> x1 (f32, residual) + x1T (bf16 [HW][C])
    ln_fused_kernel<true><<<dim3(HW / 64, BATCH), blk, 0, stream>>>(x, g1, b1, x1, x1T);
    // 2. qkv GEMM -> bf16 [3C][HW]
    gemm_mfma_kernel<0><<<dim3(HW / 128, (3 * CDIM) / 64, BATCH), blk, 0, stream>>>(
        wq_b, x1T, qkvA, nullptr, nullptr, 3 * CDIM, CDIM);
    // 3. depthwise 3x3
    dw_kernel<<<dim3(HW / 256, 3 * CDIM, BATCH), blk, 0, stream>>>(qkvA, w_dw, dwB);
    // 4. l2 norm inverses for q,k
    l2inv_kernel<<<dim3(2 * CDIM, BATCH), blk, 0, stream>>>(dwB, invq, invk);
    // 5. attn partial dot-products over pixel chunks
    attn_qk_kernel<<<dim3(HW / PCHUNK, HEADS, BATCH), blk, 0, stream>>>(
        dwB, invq, invk, temp, part);
    // 6. deterministic reduction of partials
    attn_reduce_kernel<<<dim3((BATCH * HEADS * CP * CP) / 256), blk, 0, stream>>>(part, attn);
    // 7. 3x3 conv over head channels
    headconv_kernel<<<dim3(HEADS, BATCH), blk, 0, stream>>>(attn, w_head, attn2);
    // 8. softmax over last dim
    softmax_kernel<<<dim3(HEADS, BATCH), dim3(1024), 0, stream>>>(attn2);
    // 9. out = attn @ v -> bf16 [HW][C] (pre-transposed for proj)
    av_kernel<<<dim3(HW / 256, HEADS, BATCH), blk, 0, stream>>>(attn2, dwB, attn_outT);
    // 10. proj GEMM + residual(x1) -> x2 f32 [C][HW]
    gemm_mfma_kernel<1><<<dim3(HW / 128, CDIM / 64, BATCH), blk, 0, stream>>>(
        wp_b, attn_outT, x2, nullptr, x1, CDIM, CDIM);
    // 11. LayerNorm2 fused -> ln2T bf16 [HW][C] only
    ln_fused_kernel<false><<<dim3(HW / 64, BATCH), blk, 0, stream>>>(
        x2, g2, b2, nullptr, ln2T);
    // 12. fc1 GEMM + bias + gelu -> y1T bf16 [HW][HIDDEN]
    gemm_mfma_kernel<3><<<dim3(HW / 128, HIDDEN / 64, BATCH), blk, 0, stream>>>(
        wf1_b, ln2T, y1T, b_fc1, nullptr, HIDDEN, CDIM);
    // 13. fc2 GEMM + bias + gelu -> y2 f32 [C][HW]
    gemm_mfma_kernel<2><<<dim3(HW / 128, CDIM / 64, BATCH), blk, 0, stream>>>(
        wf2_b, y1T, y2, b_fc2, nullptr, CDIM, HIDDEN);
    // 14. spatial gate: channel-split partials + finish
    gate_partial_kernel<<<dim3(HW / 256, CSPLIT, BATCH), blk, 0, stream>>>(
        y2, w_sa, part_g);
    gate_finish_kernel<<<dim3(BATCH * HW / 256), blk, 0, stream>>>(part_g, b_sa, gate);
    // 15. final: out = x2 + y2*gate
    final_kernel<<<dim3((int)(FULL / 256)), blk, 0, stream>>>(x2, y2, gate, out);
}

// Round 4
// 341.239 us; speedup vs baseline: 4.2121x; 1.6356x over previous
//
#include <hip/hip_runtime.h>
#include <hip/hip_bf16.h>
#include <math.h>

using bf16 = __hip_bfloat16;

static constexpr int CDIM   = 192;
static constexpr int HEADS  = 6;
static constexpr int CP     = 32;     // CDIM / HEADS
static constexpr int HIDDEN = 384;
static constexpr int HImg   = 128;
static constexpr int WImg   = 128;
static constexpr int HW     = HImg * WImg;   // 16384
static constexpr int BATCH  = 4;
static constexpr int PCHUNK = 256;    // attn contraction chunk
static constexpr int CSPLIT = 12;     // gate conv channel splits (16 ch each)

typedef __attribute__((ext_vector_type(8))) short short8;
typedef __attribute__((ext_vector_type(4))) float f32x4;
typedef __attribute__((ext_vector_type(4))) unsigned short ushort4v;
typedef __attribute__((ext_vector_type(8))) unsigned short ushort8v;

template<typename T> __device__ inline float tof(T v);
template<> __device__ inline float tof<float>(float v){ return v; }
template<> __device__ inline float tof<bf16>(bf16 v){ return __bfloat162float(v); }

template<typename T> __device__ inline T fromf(float v);
template<> __device__ inline float fromf<float>(float v){ return v; }
template<> __device__ inline bf16  fromf<bf16>(float v){ return __float2bfloat16(v); }

__device__ inline unsigned short f2bf_bits(float f){
    bf16 h = __float2bfloat16(f);
    return *reinterpret_cast<unsigned short*>(&h);
}
__device__ inline float bfbits2f(unsigned short u){
    union { unsigned int i; float f; } c; c.i = ((unsigned int)u) << 16; return c.f;
}

__device__ inline float gelu_exact(float x){
    return 0.5f * x * (1.0f + erff(x * 0.70710678118654752440f));
}

// async global(16B) -> LDS
__device__ __forceinline__ void gload16(const bf16* g, bf16* l){
    __builtin_amdgcn_global_load_lds(
        (const __attribute__((address_space(1))) void*)g,
        (__attribute__((address_space(3))) void*)l, 16, 0, 0);
}

// ---------------- merged f32 -> bf16 weight convert --------------------------
__global__ __launch_bounds__(256) void convw_kernel(
    const float* __restrict__ w_qkv, const float* __restrict__ w_proj,
    const float* __restrict__ w_fc1, const float* __restrict__ w_fc2,
    bf16* __restrict__ wq, bf16* __restrict__ wp,
    bf16* __restrict__ wf1, bf16* __restrict__ wf2)
{
    int i = blockIdx.x * 256 + threadIdx.x;
    const int n0 = 576*192, n1 = n0 + 192*192, n2 = n1 + 384*192, n3 = n2 + 192*384;
    if (i < n0)      wq[i]       = fromf<bf16>(w_qkv[i]);
    else if (i < n1) wp[i - n0]  = fromf<bf16>(w_proj[i - n0]);
    else if (i < n2) wf1[i - n1] = fromf<bf16>(w_fc1[i - n1]);
    else if (i < n3) wf2[i - n2] = fromf<bf16>(w_fc2[i - n2]);
}

// ---------------- fused LayerNorm (+optional f32 out) + bf16 transpose -------
template<bool WF32>
__global__ __launch_bounds__(256) void ln_fused_kernel(
    const float* __restrict__ in, const float* __restrict__ g,
    const float* __restrict__ b, float* __restrict__ outF, bf16* __restrict__ outT)
{
    int z = blockIdx.y, p0 = blockIdx.x * 64;
    __shared__ float tile[CDIM][65];
    __shared__ float sred[4][64], s2red[4][64];
    __shared__ float mrow[64], rrow[64];
    const float* ib = in + (size_t)z * CDIM * HW + p0;
    int tid = threadIdx.x;
    for (int j = tid; j < CDIM * 16; j += 256){
        int c = j >> 4, p4 = (j & 15) * 4;
        f32x4 v = *reinterpret_cast<const f32x4*>(ib + (size_t)c * HW + p4);
        tile[c][p4]   = v[0]; tile[c][p4+1] = v[1];
        tile[c][p4+2] = v[2]; tile[c][p4+3] = v[3];
    }
    __syncthreads();
    int p = tid & 63, q = tid >> 6;
    float s = 0.f, s2 = 0.f;
    #pragma unroll 4
    for (int c = q * 48; c < q * 48 + 48; ++c){
        float v = tile[c][p]; s += v; s2 += v * v;
    }
    sred[q][p] = s; s2red[q][p] = s2;
    __syncthreads();
    if (tid < 64){
        float ts = sred[0][tid] + sred[1][tid] + sred[2][tid] + sred[3][tid];
        float t2 = s2red[0][tid] + s2red[1][tid] + s2red[2][tid] + s2red[3][tid];
        float mean = ts * (1.0f / CDIM);
        float var  = t2 * (1.0f / CDIM) - mean * mean;
        mrow[tid] = mean;
        rrow[tid] = rsqrtf(var + 1e-5f);
    }
    __syncthreads();
    unsigned short* oT = (unsigned short*)(outT + ((size_t)z * HW + p0) * CDIM);
    for (int j = tid; j < 64 * 48; j += 256){
        int pr = j / 48, c4 = (j % 48) * 4;
        float m = mrow[pr], r = rrow[pr];
        ushort4v o;
        #pragma unroll
        for (int k = 0; k < 4; ++k){
            int c = c4 + k;
            o[k] = f2bf_bits((tile[c][pr] - m) * r * g[c] + b[c]);
        }
        *(ushort4v*)&oT[(size_t)pr * CDIM + c4] = o;
    }
    if (WF32){
        float* oF = outF + (size_t)z * CDIM * HW + p0;
        for (int j = tid; j < CDIM * 16; j += 256){
            int c = j >> 4, p4 = (j & 15) * 4;
            float gg = g[c], bb = b[c];
            f32x4 v;
            #pragma unroll
            for (int k = 0; k < 4; ++k)
                v[k] = (tile[c][p4 + k] - mrow[p4 + k]) * rrow[p4 + k] * gg + bb;
            *reinterpret_cast<f32x4*>(oF + (size_t)c * HW + p4) = v;
        }
    }
}

// ---------------- MFMA GEMM: C[M,N] = Wb[M,K] @ XT[N,K]^T, batched -----------
// EPI: 0 = bf16 out [M][HW]; 1 = f32 out + residual; 2 = bias+gelu f32 out;
//      3 = bias+gelu -> transposed bf16 out [HW][M]
template<int EPI>
__global__ __launch_bounds__(256) void gemm_mfma_kernel(
    const bf16* __restrict__ Wb, const bf16* __restrict__ XT,
    void* __restrict__ Cout, const float* __restrict__ bias,
    const float* __restrict__ res, int M, int K)
{
    __shared__ bf16 smem[12288];              // A: 64x64 (4096), B: 128x64 (8192)
    bf16* Als = smem;
    bf16* Bls = smem + 4096;
    int z  = blockIdx.z;
    int n0 = blockIdx.x * 128;
    int m0 = blockIdx.y * 64;
    const bf16* Xb = XT + (size_t)z * HW * K;
    int tid  = threadIdx.x;
    int lane = tid & 63, wid = tid >> 6;
    int wm = wid & 1, wn = wid >> 1;          // 2x2 waves, each 32m x 64n
    int r16 = lane & 15, grp = lane >> 4;

    f32x4 acc[2][4];
    #pragma unroll
    for (int i = 0; i < 2; ++i)
        #pragma unroll
        for (int j = 0; j < 4; ++j){ f32x4 zz = {0.f,0.f,0.f,0.f}; acc[i][j] = zz; }

    int nkt = K >> 6;
    for (int kt = 0; kt < nkt; ++kt){
        #pragma unroll
        for (int i = 0; i < 2; ++i){
            int s = i * 256 + tid;
            int row = s >> 3, ch = s & 7;
            const bf16* g = Wb + (size_t)(m0 + row) * K + kt * 64 + ((ch ^ (row & 7)) * 8);
            gload16(g, Als + s * 8);
        }
        #pragma unroll
        for (int i = 0; i < 4; ++i){
            int s = i * 256 + tid;
            int row = s >> 3, ch = s & 7;
            const bf16* g = Xb + (size_t)(n0 + row) * K + kt * 64 + ((ch ^ (row & 7)) * 8);
            gload16(g, Bls + s * 8);
        }
        asm volatile("s_waitcnt vmcnt(0)" ::: "memory");
        __syncthreads();
        #pragma unroll
        for (int ks = 0; ks < 2; ++ks){
            int kel = ks * 32 + grp * 8;
            short8 a[2], b[4];
            #pragma unroll
            for (int fi = 0; fi < 2; ++fi){
                int row = wm * 32 + fi * 16 + r16;
                a[fi] = *reinterpret_cast<const short8*>(Als + row * 64 + (kel ^ ((row & 7) * 8)));
            }
            #pragma unroll
            for (int fj = 0; fj < 4; ++fj){
                int row = wn * 64 + fj * 16 + r16;
                b[fj] = *reinterpret_cast<const short8*>(Bls + row * 64 + (kel ^ ((row & 7) * 8)));
            }
            #pragma unroll
            for (int fi = 0; fi < 2; ++fi)
                #pragma unroll
                for (int fj = 0; fj < 4; ++fj)
                    acc[fi][fj] = __builtin_amdgcn_mfma_f32_16x16x32_bf16(
                        a[fi], b[fj], acc[fi][fj], 0, 0, 0);
        }
        __syncthreads();
    }

    if (EPI == 3){
        unsigned short* T = (unsigned short*)smem;
        #pragma unroll
        for (int fi = 0; fi < 2; ++fi)
            #pragma unroll
            for (int fj = 0; fj < 4; ++fj){
                int nl = wn * 64 + fj * 16 + r16;
                int mb = wm * 32 + fi * 16 + grp * 4;
                #pragma unroll
                for (int rr = 0; rr < 4; ++rr){
                    float v = gelu_exact(acc[fi][fj][rr] + bias[m0 + mb + rr]);
                    T[nl * 72 + mb + rr] = f2bf_bits(v);
                }
            }
        __syncthreads();
        bf16* Y = (bf16*)Cout;
        int rrow = tid >> 1, half = tid & 1;
        const short8* srcv = reinterpret_cast<const short8*>(T + rrow * 72 + half * 32);
        short8* dstv = reinterpret_cast<short8*>(
            Y + ((size_t)z * HW + n0 + rrow) * M + m0 + half * 32);
        #pragma unroll
        for (int i = 0; i < 4; ++i) dstv[i] = srcv[i];
        return;
    }

    #pragma unroll
    for (int fi = 0; fi < 2; ++fi)
        #pragma unroll
        for (int fj = 0; fj < 4; ++fj){
            int mb = m0 + wm * 32 + fi * 16 + grp * 4;
            int n  = n0 + wn * 64 + fj * 16 + r16;
            #pragma unroll
            for (int rr = 0; rr < 4; ++rr){
                float v = acc[fi][fj][rr];
                int m = mb + rr;
                if (EPI == 0){
                    ((bf16*)Cout)[(size_t)z * M * HW + (size_t)m * HW + n] = fromf<bf16>(v);
                } else if (EPI == 1){
                    v += res[(size_t)z * M * HW + (size_t)m * HW + n];
                    ((float*)Cout)[(size_t)z * M * HW + (size_t)m * HW + n] = v;
                } else {
                    v = gelu_exact(v + bias[m]);
                    ((float*)Cout)[(size_t)z * M * HW + (size_t)m * HW + n] = v;
                }
            }
        }
}

// ---------------- depthwise 3x3 (8 px/thread) + fused q/k sum-of-squares -----
__global__ __launch_bounds__(256) void dw_kernel(
    const bf16* __restrict__ in, const float* __restrict__ wdw,
    bf16* __restrict__ out, float* __restrict__ sqp)
{
    int ch = blockIdx.y, z = blockIdx.z;
    int tid = threadIdx.x;
    int idx = blockIdx.x * 2048 + tid * 8;        // 8 contiguous pixels, one row
    int yy = idx >> 7, xx = idx & 127;            // xx multiple of 8
    const unsigned short* p =
        (const unsigned short*)(in + ((size_t)z * 3 * CDIM + ch) * HW);
    float w[9];
    #pragma unroll
    for (int t = 0; t < 9; ++t) w[t] = wdw[ch * 9 + t];
    float row[3][10];
    #pragma unroll
    for (int dy = 0; dy < 3; ++dy){
        int iy = yy + dy - 1;
        if (iy >= 0 && iy < HImg){
            const unsigned short* pr = p + iy * WImg;
            ushort8v v8 = *(const ushort8v*)(pr + xx);
            #pragma unroll
            for (int j = 0; j < 8; ++j) row[dy][j + 1] = bfbits2f(v8[j]);
            row[dy][0] = (xx > 0)          ? bfbits2f(pr[xx - 1]) : 0.f;
            row[dy][9] = (xx + 8 < WImg)   ? bfbits2f(pr[xx + 8]) : 0.f;
        } else {
            #pragma unroll
            for (int j = 0; j < 10; ++j) row[dy][j] = 0.f;
        }
    }
    ushort8v o8;
    float sq = 0.f;
    #pragma unroll
    for (int j = 0; j < 8; ++j){
        float a = 0.f;
        #pragma unroll
        for (int dy = 0; dy < 3; ++dy)
            #pragma unroll
            for (int dx = 0; dx < 3; ++dx)
                a = fmaf(w[dy * 3 + dx], row[dy][j + dx], a);
        o8[j] = f2bf_bits(a);
        sq = fmaf(a, a, sq);
    }
    *(ushort8v*)((unsigned short*)(out + ((size_t)z * 3 * CDIM + ch) * HW) + idx) = o8;
    if (ch < 2 * CDIM){
        #pragma unroll
        for (int m = 1; m < 64; m <<= 1) sq += __shfl_xor(sq, m, 64);
        __shared__ float red[4];
        if ((tid & 63) == 0) red[tid >> 6] = sq;
        __syncthreads();
        if (tid == 0)
            sqp[((size_t)ch * BATCH + z) * 8 + blockIdx.x] =
                red[0] + red[1] + red[2] + red[3];
    }
}

// ---------------- finish l2 inverses from dw partials ------------------------
__global__ __launch_bounds__(256) void sqfin_kernel(
    const float* __restrict__ sqp, float* __restrict__ invq, float* __restrict__ invk)
{
    int i = blockIdx.x * 256 + threadIdx.x;       // < 2*CDIM*BATCH = 1536
    if (i >= 2 * CDIM * BATCH) return;
    int ch = i / BATCH, z = i % BATCH;
    float s = 0.f;
    #pragma unroll
    for (int b = 0; b < 8; ++b) s += sqp[(size_t)i * 8 + b];
    float inv = 1.0f / fmaxf(sqrtf(s), 1e-12f);
    if (ch < CDIM) invq[z * CDIM + ch] = inv;
    else           invk[z * CDIM + ch - CDIM] = inv;
}

// ---------------- attn partials: per chunk of PCHUNK pixels ------------------
__global__ __launch_bounds__(256) void attn_qk_kernel(
    const bf16* __restrict__ qkv, const float* __restrict__ invq,
    const float* __restrict__ invk, const float* __restrict__ temp,
    float* __restrict__ part)
{
    int chunk = blockIdx.x;
    int h = blockIdx.y, z = blockIdx.z;
    __shared__ unsigned short qs[CP][PCHUNK + 4];
    __shared__ unsigned short ks[CP][PCHUNK + 4];
    int n0 = chunk * PCHUNK;
    const unsigned short* qb = (const unsigned short*)(qkv + ((size_t)z * 3 * CDIM + h * CP) * HW);
    const unsigned short* kb = (const unsigned short*)(qkv + ((size_t)z * 3 * CDIM + CDIM + h * CP) * HW);
    for (int i = threadIdx.x; i < CP * (PCHUNK / 4); i += 256){
        int r = i >> 6, p4 = i & 63;
        *(ushort4v*)&qs[r][p4 * 4] = *(const ushort4v*)&qb[(size_t)r * HW + n0 + p4 * 4];
        *(ushort4v*)&ks[r][p4 * 4] = *(const ushort4v*)&kb[(size_t)r * HW + n0 + p4 * 4];
    }
    __syncthreads();
    int c  = threadIdx.x >> 3;
    int d0 = (threadIdx.x & 7) * 4;
    float acc[4] = {0.f, 0.f, 0.f, 0.f};
    for (int p4 = 0; p4 < PCHUNK / 4; ++p4){
        ushort4v qv = *(const ushort4v*)&qs[c][p4 * 4];
        float qf0 = bfbits2f(qv[0]), qf1 = bfbits2f(qv[1]);
        float qf2 = bfbits2f(qv[2]), qf3 = bfbits2f(qv[3]);
        #pragma unroll
        for (int j = 0; j < 4; ++j){
            ushort4v kv = *(const ushort4v*)&ks[d0 + j][p4 * 4];
            acc[j] = fmaf(qf0, bfbits2f(kv[0]),
                     fmaf(qf1, bfbits2f(kv[1]),
                     fmaf(qf2, bfbits2f(kv[2]),
                     fmaf(qf3, bfbits2f(kv[3]), acc[j]))));
        }
    }
    float sc = invq[z * CDIM + h * CP + c] * temp[h];
    size_t base = ((size_t)chunk * BATCH * HEADS + (size_t)z * HEADS + h) * CP * CP
                + c * CP + d0;
    #pragma unroll
    for (int j = 0; j < 4; ++j)
        part[base + j] = acc[j] * sc * invk[z * CDIM + h * CP + d0 + j];
}

__global__ __launch_bounds__(256) void attn_reduce_kernel(
    const float* __restrict__ part, float* __restrict__ attn)
{
    int idx = blockIdx.x * 256 + threadIdx.x;
    float s = 0.f;
    for (int ch = 0; ch < HW / PCHUNK; ++ch)
        s += part[(size_t)ch * (BATCH * HEADS * CP * CP) + idx];
    attn[idx] = s;
}

// ---------------- 3x3 conv over head-channels on [HEADS, CP, CP] -------------
__global__ __launch_bounds__(256) void headconv_kernel(
    const float* __restrict__ attn, const float* __restrict__ wh, float* __restrict__ attn2)
{
    int oh = blockIdx.x, z = blockIdx.y;
    __shared__ float wsm[HEADS * 9];
    if (threadIdx.x < HEADS * 9) wsm[threadIdx.x] = wh[oh * HEADS * 9 + threadIdx.x];
    __syncthreads();
    for (int idx = threadIdx.x; idx < CP * CP; idx += 256){
        int i = idx >> 5, j = idx & 31;
        float acc = 0.f;
        for (int ih = 0; ih < HEADS; ++ih){
            const float* ab = attn + ((size_t)(z * HEADS + ih)) * CP * CP;
            #pragma unroll
            for (int dy = 0; dy < 3; ++dy){
                int ii = i + dy - 1;
                if (ii < 0 || ii >= CP) continue;
                #pragma unroll
                for (int dx = 0; dx < 3; ++dx){
                    int jj = j + dx - 1;
                    if (jj < 0 || jj >= CP) continue;
                    acc += wsm[ih * 9 + dy * 3 + dx] * ab[ii * CP + jj];
                }
            }
        }
        attn2[((size_t)(z * HEADS + oh)) * CP * CP + idx] = acc;
    }
}

// ---------------- softmax over last dim (32) ---------------------------------
__global__ __launch_bounds__(1024) void softmax_kernel(float* __restrict__ attn2)
{
    int h = blockIdx.x, z = blockIdx.y;
    float* p = attn2 + ((size_t)(z * HEADS + h)) * CP * CP;
    int r = threadIdx.x >> 5, j = threadIdx.x & 31;
    float v = p[r * CP + j];
    float mx = v;
    #pragma unroll
    for (int m = 1; m < 32; m <<= 1) mx = fmaxf(mx, __shfl_xor(mx, m, 32));
    float e = expf(v - mx);
    float sum = e;
    #pragma unroll
    for (int m = 1; m < 32; m <<= 1) sum += __shfl_xor(sum, m, 32);
    p[r * CP + j] = e / sum;
}

// ---------------- out = attn2 @ v -> transposed bf16 [HW][C] -----------------
__global__ __launch_bounds__(256) void av_kernel(
    const float* __restrict__ attn2, const bf16* __restrict__ qkv, bf16* __restrict__ outT)
{
    int h = blockIdx.y, z = blockIdx.z;
    int tid = threadIdx.x;
    int n = blockIdx.x * 256 + tid;
    __shared__ float As[CP][CP];
    __shared__ unsigned short ot[256][36];
    for (int i = tid; i < CP * CP; i += 256)
        As[i >> 5][i & 31] = attn2[((size_t)(z * HEADS + h)) * CP * CP + i];
    __syncthreads();
    const bf16* vb = qkv + ((size_t)z * 3 * CDIM + 2 * CDIM + h * CP) * HW + n;
    float vreg[CP];
    #pragma unroll
    for (int d = 0; d < CP; ++d) vreg[d] = tof<bf16>(vb[(size_t)d * HW]);
    for (int c = 0; c < CP; ++c){
        float acc = 0.f;
        #pragma unroll
        for (int d = 0; d < CP; ++d) acc = fmaf(As[c][d], vreg[d], acc);
        ot[tid][c] = f2bf_bits(acc);
    }
    __syncthreads();
    unsigned short* ob = (unsigned short*)outT
        + ((size_t)z * HW + (size_t)blockIdx.x * 256) * CDIM + h * CP;
    for (int j = tid; j < 256 * 8; j += 256){
        int row = j >> 3, q4 = (j & 7) * 4;
        *(ushort4v*)&ob[(size_t)row * CDIM + q4] = *(ushort4v*)&ot[row][q4];
    }
}

// ---------------- spatial gate partials (16 ch/block, 4 px/thread) -----------
__global__ __launch_bounds__(256) void gate_partial_kernel(
    const float* __restrict__ y, const float* __restrict__ wsa,
    float* __restrict__ part_g)
{
    int cs = blockIdx.y, z = blockIdx.z;
    __shared__ float wsm[16 * 9];
    if (threadIdx.x < 144) wsm[threadIdx.x] = wsa[cs * 144 + threadIdx.x];
    __syncthreads();
    int n4 = (blockIdx.x * 256 + threadIdx.x) * 4;
    int yy = n4 >> 7, xx = n4 & 127;              // xx multiple of 4
    const float* yb = y + (size_t)z * CDIM * HW + (size_t)cs * 16 * HW;
    float acc[4] = {0.f, 0.f, 0.f, 0.f};
    for (int c = 0; c < 16; ++c){
        const float* pc = yb + (size_t)c * HW;
        #pragma unroll
        for (int dy = 0; dy < 3; ++dy){
            int iy = yy + dy - 1;
            if (iy < 0 || iy >= HImg) continue;
            const float* pr = pc + iy * WImg;
            f32x4 v = *(const f32x4*)(pr + xx);
            float e0 = (xx > 0)        ? pr[xx - 1] : 0.f;
            float e5 = (xx + 4 < WImg) ? pr[xx + 4] : 0.f;
            float e[6] = {e0, v[0], v[1], v[2], v[3], e5};
            const float* wr = &wsm[c * 9 + dy * 3];
            #pragma unroll
            for (int j = 0; j < 4; ++j)
                acc[j] = fmaf(wr[0], e[j],
                         fmaf(wr[1], e[j + 1],
                         fmaf(wr[2], e[j + 2], acc[j])));
        }
    }
    f32x4 o = {acc[0], acc[1], acc[2], acc[3]};
    *(f32x4*)&part_g[((size_t)cs * BATCH + z) * HW + n4] = o;
}

__global__ __launch_bounds__(256) void gate_finish_kernel(
    const float* __restrict__ part_g, const float* __restrict__ bsa,
    float* __restrict__ gate)
{
    int i4 = (blockIdx.x * 256 + threadIdx.x) * 4;   // < BATCH*HW
    float b0 = bsa[0];
    f32x4 acc = {b0, b0, b0, b0};
    #pragma unroll
    for (int cs = 0; cs < CSPLIT; ++cs){
        f32x4 v = *(const f32x4*)&part_g[(size_t)cs * BATCH * HW + i4];
        #pragma unroll
        for (int j = 0; j < 4; ++j) acc[j] += v[j];
    }
    f32x4 o;
    #pragma unroll
    for (int j = 0; j < 4; ++j) o[j] = 1.0f / (1.0f + expf(-acc[j]));
    *(f32x4*)&gate[i4] = o;
}

// ---------------- final: out = x2 + y2 * gate (4 px/thread) ------------------
__global__ __launch_bounds__(256) void final_kernel(
    const float* __restrict__ x2, const float* __restrict__ y2,
    const float* __restrict__ gate, float* __restrict__ out)
{
    size_t i4 = ((size_t)blockIdx.x * 256 + threadIdx.x) * 4;
    int n = (int)(i4 % HW);
    int z = (int)(i4 / ((size_t)CDIM * HW));
    f32x4 a = *(const f32x4*)(x2 + i4);
    f32x4 b = *(const f32x4*)(y2 + i4);
    f32x4 g = *(const f32x4*)(gate + (size_t)z * HW + n);
    f32x4 o;
    #pragma unroll
    for (int j = 0; j < 4; ++j) o[j] = a[j] + b[j] * g[j];
    *(f32x4*)(out + i4) = o;
}

extern "C" void kernel_launch(void* const* d_in, const int* in_sizes, int n_in,
                              void* d_out, int out_size, void* d_ws, size_t ws_size,
                              hipStream_t stream)
{
    const float* x      = (const float*)d_in[0];
    const float* g1     = (const float*)d_in[1];
    const float* b1     = (const float*)d_in[2];
    const float* w_qkv  = (const float*)d_in[3];
    const float* w_dw   = (const float*)d_in[4];
    const float* temp   = (const float*)d_in[5];
    const float* w_head = (const float*)d_in[6];
    const float* w_proj = (const float*)d_in[7];
    const float* g2     = (const float*)d_in[8];
    const float* b2     = (const float*)d_in[9];
    const float* w_fc1  = (const float*)d_in[10];
    const float* b_fc1  = (const float*)d_in[11];
    const float* w_fc2  = (const float*)d_in[12];
    const float* b_fc2  = (const float*)d_in[13];
    const float* w_sa   = (const float*)d_in[14];
    const float* b_sa   = (const float*)d_in[15];
    float* out = (float*)d_out;

    char* ws = (char*)d_ws;
    const size_t FULL = (size_t)BATCH * CDIM * HW;      // 12.58M elems

    // R0: FULL f32  (x1 -> y2)
    float* x1 = (float*)ws;
    float* y2 = x1;
    // R1 (6F bytes): qkvA bf16 3FULL -> attn_outT bf16 -> {ln2T bf16 | y1T bf16}
    char* R1 = ws + FULL * 4;
    bf16*  qkvA      = (bf16*)R1;
    bf16*  attn_outT = (bf16*)R1;
    bf16*  ln2T      = (bf16*)R1;
    bf16*  y1T       = (bf16*)(R1 + FULL * 2);
    // R2 (6F bytes): x1T bf16 -> dwB bf16 3FULL -> x2 f32
    char* R2 = R1 + FULL * 3 * 2;
    bf16*  x1T = (bf16*)R2;
    bf16*  dwB = (bf16*)R2;
    float* x2  = (float*)R2;
    // small region
    char* SM = R2 + FULL * 3 * 2;
    float* invq  = (float*)SM;                              // B*CDIM
    float* invk  = invq + BATCH * CDIM;
    float* attn  = invk + BATCH * CDIM;                     // B*HEADS*CP*CP
    float* attn2 = attn + BATCH * HEADS * CP * CP;
    float* gate  = attn2 + BATCH * HEADS * CP * CP;         // B*HW
    float* part  = gate + BATCH * HW;                       // 64*B*HEADS*CP*CP (6.3MB)
    float* part_g = part;                                   // aliases part
    float* sqp    = part;                                   // aliases part (dw partials)
    bf16* wq_b  = (bf16*)(part + (HW / PCHUNK) * BATCH * HEADS * CP * CP);
    bf16* wp_b  = wq_b  + 576 * 192;
    bf16* wf1_b = wp_b  + 192 * 192;
    bf16* wf2_b = wf1_b + 384 * 192;

    dim3 blk(256);

    // 0. merged weight conversion to bf16
    convw_kernel<<<dim3((294912 + 255) / 256), blk, 0, stream>>>(
        w_qkv, w_proj, w_fc1, w_fc2, wq_b, wp_b, wf1_b, wf2_b);
    // 1. LayerNorm1 fused: x -> x1 (f32, residual) + x1T (bf16 [HW][C])
    ln_fused_kernel<true><<<dim3(HW / 64, BATCH), blk, 0, stream>>>(x, g1, b1, x1, x1T);
    // 2. qkv GEMM -> bf16 [3C][HW]
    gemm_mfma_kernel<0><<<dim3(HW / 128, (3 * CDIM) / 64, BATCH), blk, 0, stream>>>(
        wq_b, x1T, qkvA, nullptr, nullptr, 3 * CDIM, CDIM);
    // 3. depthwise 3x3 (8 px/thread) + fused q/k sumsq partials
    dw_kernel<<<dim3(HW / 2048, 3 * CDIM, BATCH), blk, 0, stream>>>(qkvA, w_dw, dwB, sqp);
    // 4. finish l2 inverses
    sqfin_kernel<<<dim3(6), blk, 0, stream>>>(sqp, invq, invk);
    // 5. attn partial dot-products over pixel chunks
    attn_qk_kernel<<<dim3(HW / PCHUNK, HEADS, BATCH), blk, 0, stream>>>(
        dwB, invq, invk, temp, part);
    // 6. deterministic reduction of partials
    attn_reduce_kernel<<<dim3((BATCH * HEADS * CP * CP) / 256), blk, 0, stream>>>(part, attn);
    // 7. 3x3 conv over head channels
    headconv_kernel<<<dim3(HEADS, BATCH), blk, 0, stream>>>(attn, w_head, attn2);
    // 8. softmax over last dim
    softmax_kernel<<<dim3(HEADS, BATCH), dim3(1024), 0, stream>>>(attn2);
    // 9. out = attn @ v -> bf16 [HW][C] (pre-transposed for proj)
    av_kernel<<<dim3(HW / 256, HEADS, BATCH), blk, 0, stream>>>(attn2, dwB, attn_outT);
    // 10. proj GEMM + residual(x1) -> x2 f32 [C][HW]
    gemm_mfma_kernel<1><<<dim3(HW / 128, CDIM / 64, BATCH), blk, 0, stream>>>(
        wp_b, attn_outT, x2, nullptr, x1, CDIM, CDIM);
    // 11. LayerNorm2 fused -> ln2T bf16 [HW][C] only
    ln_fused_kernel<false><<<dim3(HW / 64, BATCH), blk, 0, stream>>>(
        x2, g2, b2, nullptr, ln2T);
    // 12. fc1 GEMM + bias + gelu -> y1T bf16 [HW][HIDDEN]
    gemm_mfma_kernel<3><<<dim3(HW / 128, HIDDEN / 64, BATCH), blk, 0, stream>>>(
        wf1_b, ln2T, y1T, b_fc1, nullptr, HIDDEN, CDIM);
    // 13. fc2 GEMM + bias + gelu -> y2 f32 [C][HW]
    gemm_mfma_kernel<2><<<dim3(HW / 128, CDIM / 64, BATCH), blk, 0, stream>>>(
        wf2_b, y1T, y2, b_fc2, nullptr, CDIM, HIDDEN);
    // 14. spatial gate: channel-split partials (4 px/thread) + finish
    gate_partial_kernel<<<dim3(HW / 1024, CSPLIT, BATCH), blk, 0, stream>>>(
        y2, w_sa, part_g);
    gate_finish_kernel<<<dim3(BATCH * HW / 1024), blk, 0, stream>>>(part_g, b_sa, gate);
    // 15. final: out = x2 + y2*gate (4 px/thread)
    final_kernel<<<dim3((int)(FULL / 1024)), blk, 0, stream>>>(x2, y2, gate, out);
}

// Round 5
// 287.382 us; speedup vs baseline: 5.0014x; 1.1874x over previous
//
#include <hip/hip_runtime.h>
#include <hip/hip_bf16.h>
#include <math.h>

using bf16 = __hip_bfloat16;

static constexpr int CDIM   = 192;
static constexpr int HEADS  = 6;
static constexpr int CP     = 32;     // CDIM / HEADS
static constexpr int HIDDEN = 384;
static constexpr int HImg   = 128;
static constexpr int WImg   = 128;
static constexpr int HW     = HImg * WImg;   // 16384
static constexpr int BATCH  = 4;
static constexpr int PCHUNK = 256;    // attn contraction chunk
static constexpr int CSPLIT = 12;     // gate conv channel splits (16 ch each)

typedef __attribute__((ext_vector_type(8))) short short8;
typedef __attribute__((ext_vector_type(4))) float f32x4;
typedef __attribute__((ext_vector_type(4))) unsigned short ushort4v;
typedef __attribute__((ext_vector_type(8))) unsigned short ushort8v;

template<typename T> __device__ inline float tof(T v);
template<> __device__ inline float tof<float>(float v){ return v; }
template<> __device__ inline float tof<bf16>(bf16 v){ return __bfloat162float(v); }

template<typename T> __device__ inline T fromf(float v);
template<> __device__ inline float fromf<float>(float v){ return v; }
template<> __device__ inline bf16  fromf<bf16>(float v){ return __float2bfloat16(v); }

__device__ inline unsigned short f2bf_bits(float f){
    bf16 h = __float2bfloat16(f);
    return *reinterpret_cast<unsigned short*>(&h);
}
__device__ inline float bfbits2f(unsigned short u){
    union { unsigned int i; float f; } c; c.i = ((unsigned int)u) << 16; return c.f;
}

__device__ inline float gelu_exact(float x){
    return 0.5f * x * (1.0f + erff(x * 0.70710678118654752440f));
}

// load 4 consecutive elems as float
__device__ inline void load4f(const float* p, float* f){
    f32x4 v = *reinterpret_cast<const f32x4*>(p);
    f[0]=v[0]; f[1]=v[1]; f[2]=v[2]; f[3]=v[3];
}
__device__ inline void load4f(const bf16* p, float* f){
    ushort4v v = *reinterpret_cast<const ushort4v*>(p);
    f[0]=bfbits2f(v[0]); f[1]=bfbits2f(v[1]); f[2]=bfbits2f(v[2]); f[3]=bfbits2f(v[3]);
}

// async global(16B) -> LDS
__device__ __forceinline__ void gload16(const bf16* g, bf16* l){
    __builtin_amdgcn_global_load_lds(
        (const __attribute__((address_space(1))) void*)g,
        (__attribute__((address_space(3))) void*)l, 16, 0, 0);
}

// ---------------- merged f32 -> bf16 weight convert --------------------------
__global__ __launch_bounds__(256) void convw_kernel(
    const float* __restrict__ w_qkv, const float* __restrict__ w_proj,
    const float* __restrict__ w_fc1, const float* __restrict__ w_fc2,
    bf16* __restrict__ wq, bf16* __restrict__ wp,
    bf16* __restrict__ wf1, bf16* __restrict__ wf2)
{
    int i = blockIdx.x * 256 + threadIdx.x;
    const int n0 = 576*192, n1 = n0 + 192*192, n2 = n1 + 384*192, n3 = n2 + 192*384;
    if (i < n0)      wq[i]       = fromf<bf16>(w_qkv[i]);
    else if (i < n1) wp[i - n0]  = fromf<bf16>(w_proj[i - n0]);
    else if (i < n2) wf1[i - n1] = fromf<bf16>(w_fc1[i - n1]);
    else if (i < n3) wf2[i - n2] = fromf<bf16>(w_fc2[i - n2]);
}

// ---------------- fused LayerNorm (+optional bf16 [C][HW] copy) + transpose --
// in: T [C][HW]; outT: bf16 [HW][C]; resF (if WRES): bf16 [C][HW] of normed vals
template<typename T, bool WRES>
__global__ __launch_bounds__(256) void ln_fused_kernel(
    const T* __restrict__ in, const float* __restrict__ g,
    const float* __restrict__ b, bf16* __restrict__ resF, bf16* __restrict__ outT)
{
    int z = blockIdx.y, p0 = blockIdx.x * 64;
    __shared__ float tile[CDIM][65];
    __shared__ float sred[4][64], s2red[4][64];
    __shared__ float mrow[64], rrow[64];
    const T* ib = in + (size_t)z * CDIM * HW + p0;
    int tid = threadIdx.x;
    for (int j = tid; j < CDIM * 16; j += 256){
        int c = j >> 4, p4 = (j & 15) * 4;
        float f[4];
        load4f(ib + (size_t)c * HW + p4, f);
        tile[c][p4]   = f[0]; tile[c][p4+1] = f[1];
        tile[c][p4+2] = f[2]; tile[c][p4+3] = f[3];
    }
    __syncthreads();
    int p = tid & 63, q = tid >> 6;
    float s = 0.f, s2 = 0.f;
    #pragma unroll 4
    for (int c = q * 48; c < q * 48 + 48; ++c){
        float v = tile[c][p]; s += v; s2 += v * v;
    }
    sred[q][p] = s; s2red[q][p] = s2;
    __syncthreads();
    if (tid < 64){
        float ts = sred[0][tid] + sred[1][tid] + sred[2][tid] + sred[3][tid];
        float t2 = s2red[0][tid] + s2red[1][tid] + s2red[2][tid] + s2red[3][tid];
        float mean = ts * (1.0f / CDIM);
        float var  = t2 * (1.0f / CDIM) - mean * mean;
        mrow[tid] = mean;
        rrow[tid] = rsqrtf(var + 1e-5f);
    }
    __syncthreads();
    unsigned short* oT = (unsigned short*)(outT + ((size_t)z * HW + p0) * CDIM);
    for (int j = tid; j < 64 * 48; j += 256){
        int pr = j / 48, c4 = (j % 48) * 4;
        float m = mrow[pr], r = rrow[pr];
        ushort4v o;
        #pragma unroll
        for (int k = 0; k < 4; ++k){
            int c = c4 + k;
            o[k] = f2bf_bits((tile[c][pr] - m) * r * g[c] + b[c]);
        }
        *(ushort4v*)&oT[(size_t)pr * CDIM + c4] = o;
    }
    if (WRES){
        unsigned short* oF = (unsigned short*)resF + (size_t)z * CDIM * HW + p0;
        for (int j = tid; j < CDIM * 16; j += 256){
            int c = j >> 4, p4 = (j & 15) * 4;
            float gg = g[c], bb = b[c];
            ushort4v v;
            #pragma unroll
            for (int k = 0; k < 4; ++k)
                v[k] = f2bf_bits((tile[c][p4 + k] - mrow[p4 + k]) * rrow[p4 + k] * gg + bb);
            *(ushort4v*)&oF[(size_t)c * HW + p4] = v;
        }
    }
}

// ---------------- MFMA GEMM: C[M,N] = Wb[M,K] @ XT[N,K]^T, batched -----------
// EPI: 0 = bf16 out [M][HW]; 1 = bf16 out + bf16 residual; 2 = bias+gelu bf16 out;
//      3 = bias+gelu -> transposed bf16 out [HW][M]
template<int EPI>
__global__ __launch_bounds__(256) void gemm_mfma_kernel(
    const bf16* __restrict__ Wb, const bf16* __restrict__ XT,
    void* __restrict__ Cout, const float* __restrict__ bias,
    const bf16* __restrict__ res, int M, int K)
{
    __shared__ bf16 smem[12288];              // A: 64x64 (4096), B: 128x64 (8192)
    bf16* Als = smem;
    bf16* Bls = smem + 4096;
    int z  = blockIdx.z;
    int n0 = blockIdx.x * 128;
    int m0 = blockIdx.y * 64;
    const bf16* Xb = XT + (size_t)z * HW * K;
    int tid  = threadIdx.x;
    int lane = tid & 63, wid = tid >> 6;
    int wm = wid & 1, wn = wid >> 1;          // 2x2 waves, each 32m x 64n
    int r16 = lane & 15, grp = lane >> 4;

    f32x4 acc[2][4];
    #pragma unroll
    for (int i = 0; i < 2; ++i)
        #pragma unroll
        for (int j = 0; j < 4; ++j){ f32x4 zz = {0.f,0.f,0.f,0.f}; acc[i][j] = zz; }

    int nkt = K >> 6;
    for (int kt = 0; kt < nkt; ++kt){
        #pragma unroll
        for (int i = 0; i < 2; ++i){
            int s = i * 256 + tid;
            int row = s >> 3, ch = s & 7;
            const bf16* g = Wb + (size_t)(m0 + row) * K + kt * 64 + ((ch ^ (row & 7)) * 8);
            gload16(g, Als + s * 8);
        }
        #pragma unroll
        for (int i = 0; i < 4; ++i){
            int s = i * 256 + tid;
            int row = s >> 3, ch = s & 7;
            const bf16* g = Xb + (size_t)(n0 + row) * K + kt * 64 + ((ch ^ (row & 7)) * 8);
            gload16(g, Bls + s * 8);
        }
        asm volatile("s_waitcnt vmcnt(0)" ::: "memory");
        __syncthreads();
        #pragma unroll
        for (int ks = 0; ks < 2; ++ks){
            int kel = ks * 32 + grp * 8;
            short8 a[2], b[4];
            #pragma unroll
            for (int fi = 0; fi < 2; ++fi){
                int row = wm * 32 + fi * 16 + r16;
                a[fi] = *reinterpret_cast<const short8*>(Als + row * 64 + (kel ^ ((row & 7) * 8)));
            }
            #pragma unroll
            for (int fj = 0; fj < 4; ++fj){
                int row = wn * 64 + fj * 16 + r16;
                b[fj] = *reinterpret_cast<const short8*>(Bls + row * 64 + (kel ^ ((row & 7) * 8)));
            }
            #pragma unroll
            for (int fi = 0; fi < 2; ++fi)
                #pragma unroll
                for (int fj = 0; fj < 4; ++fj)
                    acc[fi][fj] = __builtin_amdgcn_mfma_f32_16x16x32_bf16(
                        a[fi], b[fj], acc[fi][fj], 0, 0, 0);
        }
        __syncthreads();
    }

    if (EPI == 3){
        unsigned short* T = (unsigned short*)smem;
        #pragma unroll
        for (int fi = 0; fi < 2; ++fi)
            #pragma unroll
            for (int fj = 0; fj < 4; ++fj){
                int nl = wn * 64 + fj * 16 + r16;
                int mb = wm * 32 + fi * 16 + grp * 4;
                #pragma unroll
                for (int rr = 0; rr < 4; ++rr){
                    float v = gelu_exact(acc[fi][fj][rr] + bias[m0 + mb + rr]);
                    T[nl * 72 + mb + rr] = f2bf_bits(v);
                }
            }
        __syncthreads();
        bf16* Y = (bf16*)Cout;
        int rrow = tid >> 1, half = tid & 1;
        const short8* srcv = reinterpret_cast<const short8*>(T + rrow * 72 + half * 32);
        short8* dstv = reinterpret_cast<short8*>(
            Y + ((size_t)z * HW + n0 + rrow) * M + m0 + half * 32);
        #pragma unroll
        for (int i = 0; i < 4; ++i) dstv[i] = srcv[i];
        return;
    }

    bf16* Cb = (bf16*)Cout;
    #pragma unroll
    for (int fi = 0; fi < 2; ++fi)
        #pragma unroll
        for (int fj = 0; fj < 4; ++fj){
            int mb = m0 + wm * 32 + fi * 16 + grp * 4;
            int n  = n0 + wn * 64 + fj * 16 + r16;
            #pragma unroll
            for (int rr = 0; rr < 4; ++rr){
                float v = acc[fi][fj][rr];
                int m = mb + rr;
                if (EPI == 1) v += tof<bf16>(res[(size_t)z * M * HW + (size_t)m * HW + n]);
                if (EPI == 2) v = gelu_exact(v + bias[m]);
                Cb[(size_t)z * M * HW + (size_t)m * HW + n] = fromf<bf16>(v);
            }
        }
}

// ---------------- depthwise 3x3 (8 px/thread, shfl halos) + q/k sumsq --------
__global__ __launch_bounds__(256) void dw_kernel(
    const bf16* __restrict__ in, const float* __restrict__ wdw,
    bf16* __restrict__ out, float* __restrict__ sqp)
{
    int ch = blockIdx.y, z = blockIdx.z;
    int tid = threadIdx.x;
    int idx = blockIdx.x * 2048 + tid * 8;        // 8 contiguous pixels, one row
    int yy = idx >> 7, xx = idx & 127;            // xx multiple of 8
    const unsigned short* p =
        (const unsigned short*)(in + ((size_t)z * 3 * CDIM + ch) * HW);
    float w[9];
    #pragma unroll
    for (int t = 0; t < 9; ++t) w[t] = wdw[ch * 9 + t];
    float f[3][8], lf[3], rf[3];
    #pragma unroll
    for (int dy = 0; dy < 3; ++dy){
        int iy = yy + dy - 1;
        if (iy >= 0 && iy < HImg){
            ushort8v v8 = *(const ushort8v*)(p + iy * WImg + xx);
            #pragma unroll
            for (int j = 0; j < 8; ++j) f[dy][j] = bfbits2f(v8[j]);
        } else {
            #pragma unroll
            for (int j = 0; j < 8; ++j) f[dy][j] = 0.f;
        }
        float l = __shfl_up(f[dy][7], 1);
        float r = __shfl_down(f[dy][0], 1);
        lf[dy] = (xx == 0) ? 0.f : l;             // 16 lanes per image row
        rf[dy] = (xx + 8 >= WImg) ? 0.f : r;
    }
    ushort8v o8;
    float sq = 0.f;
    #pragma unroll
    for (int j = 0; j < 8; ++j){
        float a = 0.f;
        #pragma unroll
        for (int dy = 0; dy < 3; ++dy){
            float e0 = (j == 0) ? lf[dy] : f[dy][j - 1];
            float e2 = (j == 7) ? rf[dy] : f[dy][j + 1];
            a = fmaf(w[dy*3], e0, fmaf(w[dy*3+1], f[dy][j], fmaf(w[dy*3+2], e2, a)));
        }
        o8[j] = f2bf_bits(a);
        sq = fmaf(a, a, sq);
    }
    *(ushort8v*)((unsigned short*)(out + ((size_t)z * 3 * CDIM + ch) * HW) + idx) = o8;
    if (ch < 2 * CDIM){
        #pragma unroll
        for (int m = 1; m < 64; m <<= 1) sq += __shfl_xor(sq, m, 64);
        __shared__ float red[4];
        if ((tid & 63) == 0) red[tid >> 6] = sq;
        __syncthreads();
        if (tid == 0)
            sqp[((size_t)ch * BATCH + z) * 8 + blockIdx.x] =
                red[0] + red[1] + red[2] + red[3];
    }
}

// ---------------- attn partials (inline l2-inv from sqp) ---------------------
__global__ __launch_bounds__(256) void attn_qk_kernel(
    const bf16* __restrict__ qkv, const float* __restrict__ sqp,
    const float* __restrict__ temp, float* __restrict__ part)
{
    int chunk = blockIdx.x;
    int h = blockIdx.y, z = blockIdx.z;
    __shared__ unsigned short qs[CP][PCHUNK + 4];
    __shared__ unsigned short ks[CP][PCHUNK + 4];
    __shared__ float invqs[CP], invks[CP];
    int tid = threadIdx.x;
    if (tid < 2 * CP){
        int which = tid >> 5, cc = tid & 31;
        int ch = which * CDIM + h * CP + cc;
        const float* sp = &sqp[((size_t)ch * BATCH + z) * 8];
        float s = sp[0]+sp[1]+sp[2]+sp[3]+sp[4]+sp[5]+sp[6]+sp[7];
        float inv = 1.0f / fmaxf(sqrtf(s), 1e-12f);
        (which ? invks : invqs)[cc] = inv;
    }
    int n0 = chunk * PCHUNK;
    const unsigned short* qb = (const unsigned short*)(qkv + ((size_t)z * 3 * CDIM + h * CP) * HW);
    const unsigned short* kb = (const unsigned short*)(qkv + ((size_t)z * 3 * CDIM + CDIM + h * CP) * HW);
    for (int i = tid; i < CP * (PCHUNK / 4); i += 256){
        int r = i >> 6, p4 = i & 63;
        *(ushort4v*)&qs[r][p4 * 4] = *(const ushort4v*)&qb[(size_t)r * HW + n0 + p4 * 4];
        *(ushort4v*)&ks[r][p4 * 4] = *(const ushort4v*)&kb[(size_t)r * HW + n0 + p4 * 4];
    }
    __syncthreads();
    int c  = tid >> 3;
    int d0 = (tid & 7) * 4;
    float acc[4] = {0.f, 0.f, 0.f, 0.f};
    for (int p4 = 0; p4 < PCHUNK / 4; ++p4){
        ushort4v qv = *(const ushort4v*)&qs[c][p4 * 4];
        float qf0 = bfbits2f(qv[0]), qf1 = bfbits2f(qv[1]);
        float qf2 = bfbits2f(qv[2]), qf3 = bfbits2f(qv[3]);
        #pragma unroll
        for (int j = 0; j < 4; ++j){
            ushort4v kv = *(const ushort4v*)&ks[d0 + j][p4 * 4];
            acc[j] = fmaf(qf0, bfbits2f(kv[0]),
                     fmaf(qf1, bfbits2f(kv[1]),
                     fmaf(qf2, bfbits2f(kv[2]),
                     fmaf(qf3, bfbits2f(kv[3]), acc[j]))));
        }
    }
    float sc = invqs[c] * temp[h];
    size_t base = ((size_t)chunk * BATCH * HEADS + (size_t)z * HEADS + h) * CP * CP
                + c * CP + d0;
    #pragma unroll
    for (int j = 0; j < 4; ++j)
        part[base + j] = acc[j] * sc * invks[d0 + j];
}

__global__ __launch_bounds__(256) void attn_reduce_kernel(
    const float* __restrict__ part, float* __restrict__ attn)
{
    int idx = blockIdx.x * 256 + threadIdx.x;
    float s = 0.f;
    for (int ch = 0; ch < HW / PCHUNK; ++ch)
        s += part[(size_t)ch * (BATCH * HEADS * CP * CP) + idx];
    attn[idx] = s;
}

// ---------------- head conv 3x3 + softmax (merged) ---------------------------
__global__ __launch_bounds__(256) void headconv_softmax_kernel(
    const float* __restrict__ attn, const float* __restrict__ wh,
    float* __restrict__ attn2)
{
    int oh = blockIdx.x, z = blockIdx.y;
    __shared__ float wsm[HEADS * 9];
    __shared__ float ain[HEADS][CP * CP];
    __shared__ float aout[CP * CP];
    int tid = threadIdx.x;
    if (tid < HEADS * 9) wsm[tid] = wh[oh * HEADS * 9 + tid];
    for (int i = tid; i < HEADS * CP * CP; i += 256)
        ain[i >> 10][i & 1023] = attn[((size_t)z * HEADS + (i >> 10)) * CP * CP + (i & 1023)];
    __syncthreads();
    for (int idx = tid; idx < CP * CP; idx += 256){
        int i = idx >> 5, j = idx & 31;
        float acc = 0.f;
        #pragma unroll
        for (int ih = 0; ih < HEADS; ++ih){
            #pragma unroll
            for (int dy = 0; dy < 3; ++dy){
                int ii = i + dy - 1;
                if (ii < 0 || ii >= CP) continue;
                #pragma unroll
                for (int dx = 0; dx < 3; ++dx){
                    int jj = j + dx - 1;
                    if (jj < 0 || jj >= CP) continue;
                    acc += wsm[ih * 9 + dy * 3 + dx] * ain[ih][ii * CP + jj];
                }
            }
        }
        aout[idx] = acc;
    }
    __syncthreads();
    // softmax: 8 lanes per row, 4 cols each
    int r = tid >> 3, l8 = tid & 7;
    float v[4];
    #pragma unroll
    for (int k = 0; k < 4; ++k) v[k] = aout[r * CP + l8 * 4 + k];
    float mx = fmaxf(fmaxf(v[0], v[1]), fmaxf(v[2], v[3]));
    #pragma unroll
    for (int m = 1; m < 8; m <<= 1) mx = fmaxf(mx, __shfl_xor(mx, m, 64));
    float sum = 0.f;
    #pragma unroll
    for (int k = 0; k < 4; ++k){ v[k] = expf(v[k] - mx); sum += v[k]; }
    #pragma unroll
    for (int m = 1; m < 8; m <<= 1) sum += __shfl_xor(sum, m, 64);
    float rs = 1.0f / sum;
    float* o = attn2 + ((size_t)z * HEADS + oh) * CP * CP + r * CP + l8 * 4;
    #pragma unroll
    for (int k = 0; k < 4; ++k) o[k] = v[k] * rs;
}

// ---------------- out = attn2 @ v -> transposed bf16 [HW][C] -----------------
__global__ __launch_bounds__(256) void av_kernel(
    const float* __restrict__ attn2, const bf16* __restrict__ qkv, bf16* __restrict__ outT)
{
    int h = blockIdx.y, z = blockIdx.z;
    int tid = threadIdx.x;
    __shared__ float As[CP][CP];
    __shared__ unsigned short Vs[CP][PCHUNK];
    __shared__ unsigned short ot[256][36];
    for (int i = tid; i < CP * CP; i += 256)
        As[i >> 5][i & 31] = attn2[((size_t)(z * HEADS + h)) * CP * CP + i];
    int n0 = blockIdx.x * 256;
    const unsigned short* vb =
        (const unsigned short*)(qkv + ((size_t)z * 3 * CDIM + 2 * CDIM + h * CP) * HW) + n0;
    for (int i = tid; i < CP * 64; i += 256){
        int d = i >> 6, p4 = (i & 63) * 4;
        *(ushort4v*)&Vs[d][p4] = *(const ushort4v*)(vb + (size_t)d * HW + p4);
    }
    __syncthreads();
    float vreg[CP];
    #pragma unroll
    for (int d = 0; d < CP; ++d) vreg[d] = bfbits2f(Vs[d][tid]);
    for (int c = 0; c < CP; ++c){
        float acc = 0.f;
        #pragma unroll
        for (int d = 0; d < CP; ++d) acc = fmaf(As[c][d], vreg[d], acc);
        ot[tid][c] = f2bf_bits(acc);
    }
    __syncthreads();
    unsigned short* ob = (unsigned short*)outT
        + ((size_t)z * HW + (size_t)n0) * CDIM + h * CP;
    for (int j = tid; j < 256 * 8; j += 256){
        int row = j >> 3, q4 = (j & 7) * 4;
        *(ushort4v*)&ob[(size_t)row * CDIM + q4] = *(ushort4v*)&ot[row][q4];
    }
}

// ---------------- spatial gate partials (16 ch/block, 8 px/thread, bf16 in) --
__global__ __launch_bounds__(256) void gate_partial_kernel(
    const bf16* __restrict__ y, const float* __restrict__ wsa,
    float* __restrict__ part_g)
{
    int cs = blockIdx.y, z = blockIdx.z;
    __shared__ float wsm[16 * 9];
    if (threadIdx.x < 144) wsm[threadIdx.x] = wsa[cs * 144 + threadIdx.x];
    __syncthreads();
    int idx = blockIdx.x * 2048 + threadIdx.x * 8;
    int yy = idx >> 7, xx = idx & 127;
    const unsigned short* yb =
        (const unsigned short*)(y + (size_t)z * CDIM * HW + (size_t)cs * 16 * HW);
    float acc[8] = {0.f,0.f,0.f,0.f,0.f,0.f,0.f,0.f};
    for (int c = 0; c < 16; ++c){
        const unsigned short* pc = yb + (size_t)c * HW;
        #pragma unroll
        for (int dy = 0; dy < 3; ++dy){
            int iy = yy + dy - 1;
            float f[8], lf, rf;
            if (iy >= 0 && iy < HImg){
                ushort8v v8 = *(const ushort8v*)(pc + iy * WImg + xx);
                #pragma unroll
                for (int j = 0; j < 8; ++j) f[j] = bfbits2f(v8[j]);
            } else {
                #pragma unroll
                for (int j = 0; j < 8; ++j) f[j] = 0.f;
            }
            float l = __shfl_up(f[7], 1);
            float r = __shfl_down(f[0], 1);
            lf = (xx == 0) ? 0.f : l;
            rf = (xx + 8 >= WImg) ? 0.f : r;
            const float* wr = &wsm[c * 9 + dy * 3];
            #pragma unroll
            for (int j = 0; j < 8; ++j){
                float e0 = (j == 0) ? lf : f[j - 1];
                float e2 = (j == 7) ? rf : f[j + 1];
                acc[j] = fmaf(wr[0], e0, fmaf(wr[1], f[j], fmaf(wr[2], e2, acc[j])));
            }
        }
    }
    float* og = &part_g[((size_t)cs * BATCH + z) * HW + idx];
    f32x4 o0 = {acc[0], acc[1], acc[2], acc[3]};
    f32x4 o1 = {acc[4], acc[5], acc[6], acc[7]};
    *(f32x4*)og = o0;
    *(f32x4*)(og + 4) = o1;
}

__global__ __launch_bounds__(256) void gate_finish_kernel(
    const float* __restrict__ part_g, const float* __restrict__ bsa,
    float* __restrict__ gate)
{
    int i4 = (blockIdx.x * 256 + threadIdx.x) * 4;   // < BATCH*HW
    float b0 = bsa[0];
    f32x4 acc = {b0, b0, b0, b0};
    #pragma unroll
    for (int cs = 0; cs < CSPLIT; ++cs){
        f32x4 v = *(const f32x4*)&part_g[(size_t)cs * BATCH * HW + i4];
        #pragma unroll
        for (int j = 0; j < 4; ++j) acc[j] += v[j];
    }
    f32x4 o;
    #pragma unroll
    for (int j = 0; j < 4; ++j) o[j] = 1.0f / (1.0f + expf(-acc[j]));
    *(f32x4*)&gate[i4] = o;
}

// ---------------- final: out = x2 + y2 * gate (8 px/thread, bf16 ins) --------
__global__ __launch_bounds__(256) void final_kernel(
    const bf16* __restrict__ x2, const bf16* __restrict__ y2,
    const float* __restrict__ gate, float* __restrict__ out)
{
    size_t i8 = ((size_t)blockIdx.x * 256 + threadIdx.x) * 8;
    int n = (int)(i8 % HW);
    int z = (int)(i8 / ((size_t)CDIM * HW));
    ushort8v a8 = *(const ushort8v*)((const unsigned short*)x2 + i8);
    ushort8v b8 = *(const ushort8v*)((const unsigned short*)y2 + i8);
    const float* gp = gate + (size_t)z * HW + n;
    f32x4 g0 = *(const f32x4*)gp;
    f32x4 g1 = *(const f32x4*)(gp + 4);
    f32x4 o0, o1;
    #pragma unroll
    for (int j = 0; j < 4; ++j){
        o0[j] = bfbits2f(a8[j])     + bfbits2f(b8[j])     * g0[j];
        o1[j] = bfbits2f(a8[j + 4]) + bfbits2f(b8[j + 4]) * g1[j];
    }
    *(f32x4*)(out + i8) = o0;
    *(f32x4*)(out + i8 + 4) = o1;
}

extern "C" void kernel_launch(void* const* d_in, const int* in_sizes, int n_in,
                              void* d_out, int out_size, void* d_ws, size_t ws_size,
                              hipStream_t stream)
{
    const float* x      = (const float*)d_in[0];
    const float* g1     = (const float*)d_in[1];
    const float* b1     = (const float*)d_in[2];
    const float* w_qkv  = (const float*)d_in[3];
    const float* w_dw   = (const float*)d_in[4];
    const float* temp   = (const float*)d_in[5];
    const float* w_head = (const float*)d_in[6];
    const float* w_proj = (const float*)d_in[7];
    const float* g2     = (const float*)d_in[8];
    const float* b2     = (const float*)d_in[9];
    const float* w_fc1  = (const float*)d_in[10];
    const float* b_fc1  = (const float*)d_in[11];
    const float* w_fc2  = (const float*)d_in[12];
    const float* b_fc2  = (const float*)d_in[13];
    const float* w_sa   = (const float*)d_in[14];
    const float* b_sa   = (const float*)d_in[15];
    float* out = (float*)d_out;

    char* ws = (char*)d_ws;
    const size_t FULL = (size_t)BATCH * CDIM * HW;      // 12.58M elems

    // R0 (FULL*2 B): x1 bf16 [C][HW] -> y2 bf16 [C][HW]
    bf16* x1 = (bf16*)ws;
    bf16* y2 = x1;
    // R1 (3*FULL*2 B): qkvA bf16 -> attn_outT bf16 / ln2T bf16 / y1T bf16
    char* R1 = ws + FULL * 2;
    bf16*  qkvA      = (bf16*)R1;
    bf16*  attn_outT = (bf16*)R1;
    bf16*  ln2T      = (bf16*)R1;
    bf16*  y1T       = (bf16*)(R1 + FULL * 2);
    // R2 (3*FULL*2 B): x1T bf16 -> dwB bf16 -> x2 bf16
    char* R2 = R1 + FULL * 3 * 2;
    bf16*  x1T = (bf16*)R2;
    bf16*  dwB = (bf16*)R2;
    bf16*  x2  = (bf16*)R2;
    // small region
    char* SM = R2 + FULL * 3 * 2;
    float* attn   = (float*)SM;                             // B*HEADS*CP*CP
    float* attn2  = attn + BATCH * HEADS * CP * CP;
    float* gate   = attn2 + BATCH * HEADS * CP * CP;        // B*HW
    float* sqp    = gate + BATCH * HW;                      // 2*CDIM*B*8
    float* part   = sqp + 2 * CDIM * BATCH * 8;             // 64*B*H*CP*CP (6.3MB)
    float* part_g = part;                                   // aliases part (dead)
    bf16* wq_b  = (bf16*)(part + (HW / PCHUNK) * BATCH * HEADS * CP * CP);
    bf16* wp_b  = wq_b  + 576 * 192;
    bf16* wf1_b = wp_b  + 192 * 192;
    bf16* wf2_b = wf1_b + 384 * 192;

    dim3 blk(256);

    // 0. merged weight conversion to bf16
    convw_kernel<<<dim3((294912 + 255) / 256), blk, 0, stream>>>(
        w_qkv, w_proj, w_fc1, w_fc2, wq_b, wp_b, wf1_b, wf2_b);
    // 1. LayerNorm1 fused: x -> x1 (bf16 [C][HW] residual) + x1T (bf16 [HW][C])
    ln_fused_kernel<float, true><<<dim3(HW / 64, BATCH), blk, 0, stream>>>(
        x, g1, b1, x1, x1T);
    // 2. qkv GEMM -> bf16 [3C][HW]
    gemm_mfma_kernel<0><<<dim3(HW / 128, (3 * CDIM) / 64, BATCH), blk, 0, stream>>>(
        wq_b, x1T, qkvA, nullptr, nullptr, 3 * CDIM, CDIM);
    // 3. depthwise 3x3 (8 px/thread, shfl halos) + q/k sumsq partials
    dw_kernel<<<dim3(HW / 2048, 3 * CDIM, BATCH), blk, 0, stream>>>(qkvA, w_dw, dwB, sqp);
    // 4. attn partial dot-products (inline l2-inv)
    attn_qk_kernel<<<dim3(HW / PCHUNK, HEADS, BATCH), blk, 0, stream>>>(
        dwB, sqp, temp, part);
    // 5. deterministic reduction of partials
    attn_reduce_kernel<<<dim3((BATCH * HEADS * CP * CP) / 256), blk, 0, stream>>>(part, attn);
    // 6. head conv + softmax (merged)
    headconv_softmax_kernel<<<dim3(HEADS, BATCH), blk, 0, stream>>>(attn, w_head, attn2);
    // 7. out = attn @ v -> bf16 [HW][C] (pre-transposed for proj)
    av_kernel<<<dim3(HW / 256, HEADS, BATCH), blk, 0, stream>>>(attn2, dwB, attn_outT);
    // 8. proj GEMM + residual(x1 bf16) -> x2 bf16 [C][HW]
    gemm_mfma_kernel<1><<<dim3(HW / 128, CDIM / 64, BATCH), blk, 0, stream>>>(
        wp_b, attn_outT, x2, nullptr, x1, CDIM, CDIM);
    // 9. LayerNorm2 fused (bf16 in) -> ln2T bf16 [HW][C]
    ln_fused_kernel<bf16, false><<<dim3(HW / 64, BATCH), blk, 0, stream>>>(
        x2, g2, b2, nullptr, ln2T);
    // 10. fc1 GEMM + bias + gelu -> y1T bf16 [HW][HIDDEN]
    gemm_mfma_kernel<3><<<dim3(HW / 128, HIDDEN / 64, BATCH), blk, 0, stream>>>(
        wf1_b, ln2T, y1T, b_fc1, nullptr, HIDDEN, CDIM);
    // 11. fc2 GEMM + bias + gelu -> y2 bf16 [C][HW]
    gemm_mfma_kernel<2><<<dim3(HW / 128, CDIM / 64, BATCH), blk, 0, stream>>>(
        wf2_b, y1T, y2, b_fc2, nullptr, CDIM, HIDDEN);
    // 12. spatial gate: channel-split partials (8 px/thread) + finish
    gate_partial_kernel<<<dim3(HW / 2048, CSPLIT, BATCH), blk, 0, stream>>>(
        y2, w_sa, part_g);
    gate_finish_kernel<<<dim3(BATCH * HW / 1024), blk, 0, stream>>>(part_g, b_sa, gate);
    // 13. final: out = x2 + y2*gate (8 px/thread)
    final_kernel<<<dim3((int)(FULL / 2048)), blk, 0, stream>>>(x2, y2, gate, out);
}